// Round 10
// baseline (215.339 us; speedup 1.0000x reference)
//
#include <hip/hip_runtime.h>
#include <stdint.h>

#define VOCABN 64
#define EMBN   128
#define HDIM   256
#define NUMIN  7
#define BN     64
#define SN     2048
#define TWOH   512
#define SEG    32
#define SEGLEN 64

#define CZ 2.8853900818f   // 2*log2(e)
#define CF 1.4426950409f   // log2(e)

__device__ __forceinline__ float rcpf(float x){ return __builtin_amdgcn_rcpf(x); }

__device__ __forceinline__ float fast_exp2(float x){
#if __has_builtin(__builtin_amdgcn_exp2f)
    return __builtin_amdgcn_exp2f(x);
#else
    return exp2f(x);
#endif
}

// v_pk_fma_f32 with src0 broadcast from LO half (result.lo and .hi both use src0.lo)
__device__ __forceinline__ float2 pk_fma_blo(float2 a, float2 b, float2 c){
    float2 d;
    asm("v_pk_fma_f32 %0, %1, %2, %3 op_sel_hi:[0,1,1]" : "=v"(d) : "v"(a), "v"(b), "v"(c));
    return d;
}
// v_pk_fma_f32 with src0 broadcast from HI half
__device__ __forceinline__ float2 pk_fma_bhi(float2 a, float2 b, float2 c){
    float2 d;
    asm("v_pk_fma_f32 %0, %1, %2, %3 op_sel:[1,0,0] op_sel_hi:[1,1,1]" : "=v"(d) : "v"(a), "v"(b), "v"(c));
    return d;
}

// pack two f32 -> two bf16 (RNE) in one dword: lo16 = bf16(a), hi16 = bf16(b)
__device__ __forceinline__ uint32_t cvt_pk_bf16(float a, float b){
    uint32_t r;
    asm("v_cvt_pk_bf16_f32 %0, %1, %2" : "=v"(r) : "v"(a), "v"(b));
    return r;
}

// 64-lane sum via DPP; result valid in lane 63.
__device__ __forceinline__ float waveRedDpp(float x){
    x += __int_as_float(__builtin_amdgcn_update_dpp(0, __float_as_int(x), 0x111, 0xf, 0xf, false)); // row_shr:1
    x += __int_as_float(__builtin_amdgcn_update_dpp(0, __float_as_int(x), 0x112, 0xf, 0xf, false)); // row_shr:2
    x += __int_as_float(__builtin_amdgcn_update_dpp(0, __float_as_int(x), 0x114, 0xf, 0xf, false)); // row_shr:4
    x += __int_as_float(__builtin_amdgcn_update_dpp(0, __float_as_int(x), 0x118, 0xf, 0xf, false)); // row_shr:8
    x += __int_as_float(__builtin_amdgcn_update_dpp(0, __float_as_int(x), 0x142, 0xa, 0xf, false)); // row_bcast:15
    x += __int_as_float(__builtin_amdgcn_update_dpp(0, __float_as_int(x), 0x143, 0xc, 0xf, false)); // row_bcast:31
    return x;
}

// uniform X row held as 4 float2 pairs: [n0 n1][n2 n3][n4 n5][n6 evbits]
struct XRow { float2 p01, p23, p45, p6e; };
__device__ __forceinline__ XRow loadRow(const float* p){
    XRow r;
    const float4 a = *(const float4*)p;
    const float4 b = *(const float4*)(p + 4);
    r.p01 = make_float2(a.x, a.y); r.p23 = make_float2(a.z, a.w);
    r.p45 = make_float2(b.x, b.y); r.p6e = make_float2(b.z, b.w);
    return r;
}

// ---------------- K0: prepack X rows ----------------
// X'[row] = [n0 n1 n2 n3 n4 n5 n6 evByteOffsetBits]
__global__ __launch_bounds__(256) void k0_prep(const float* __restrict__ X, float* __restrict__ Xp)
{
    const int r = blockIdx.x*256 + threadIdx.x;     // r < BN*SN
    const float4* src = (const float4*)(X + (size_t)r*8);
    const float4 a = src[0], b4 = src[1];
    float4* dst = (float4*)(Xp + (size_t)r*8);
    dst[0] = make_float4(a.y, a.z, a.w, b4.x);
    dst[1] = make_float4(b4.y, b4.z, b4.w, __int_as_float((int)a.x * (HDIM*8)));
}

// ---------------- K1: fold emb/bias/num path into INTERLEAVED, PRE-SCALED tables ----------------
// T[(dir,v,j)] = float2(CZ*z-col j, CF*f-col j); U likewise (so exp2 applies directly).
__global__ __launch_bounds__(512) void k1_tables(
    const float* __restrict__ emb, const float* __restrict__ num_W, const float* __restrict__ num_b,
    const float* __restrict__ Wf, const float* __restrict__ bf,
    const float* __restrict__ Wb, const float* __restrict__ bb,
    float* __restrict__ T, float* __restrict__ U)
{
    const int blk = blockIdx.x;
    const int c = threadIdx.x;
    const int j = c & (HDIM-1);
    const int g = c >> 8;               // 0 -> z gate, 1 -> f gate
    const int col = g*HDIM + j;
    const float gs = g ? CF : CZ;
    if (blk < 2*VOCABN) {
        const int dir = blk & 1, v = blk >> 1;
        const float* W    = dir ? Wb : Wf;
        const float* bias = dir ? bb : bf;
        float acc = bias[col];
        const float* e = emb + (size_t)v*EMBN;
        #pragma unroll 8
        for (int k=0;k<EMBN;++k) acc = fmaf(e[k], W[(size_t)k*768 + col], acc);
        #pragma unroll
        for (int m=0;m<4;++m)    acc = fmaf(num_b[m], W[(size_t)(EMBN+m)*768 + col], acc);
        T[(((size_t)dir*VOCABN + v)*HDIM + j)*2 + g] = acc * gs;
    } else {
        const int dir = blk - 2*VOCABN;
        const float* W = dir ? Wb : Wf;
        #pragma unroll
        for (int i=0;i<NUMIN;++i){
            float acc = 0.f;
            #pragma unroll
            for (int m=0;m<4;++m) acc = fmaf(num_W[i*4+m], W[(size_t)(EMBN+m)*768 + col], acc);
            U[(((size_t)dir*8 + i)*HDIM + j)*2 + g] = acc * gs;
        }
    }
}

// ---------------- K2: segmented fo-pool scan, 2 channels/thread, all-VMEM feed ----------------
// MODE 0: per-segment affine coefficients a=prod(f), c=scan from 0.
// MODE 1: scan from hstart, score partials via DPP reduce, AND store h as packed bf16.
// MODE 2: scan from hstart, ctx += w[s]*h (recompute fallback, no h storage).
// MODE 3: scan from hstart, score partials only (fallback when h2 doesn't fit ws).
// Block=(b,dir,seg), 128 threads; thread j owns channels j and j+128.
// X rows: uniform VECTOR loads (laundered-zero address) -> in-order vmcnt pipelining,
// depth-4 register ring. T rows: depth-2 register ring, saddr + 32-bit voffset.
template<int MODE>
__global__ __launch_bounds__(128, 4) void k2_scan(
    const float* __restrict__ Xp, const float* __restrict__ T, const float* __restrict__ U,
    const float* __restrict__ Mu, const float* __restrict__ w,
    const float* __restrict__ hstart,
    float* __restrict__ aArr, float* __restrict__ cArr,
    float* __restrict__ swp, float* __restrict__ ctxp, uint32_t* __restrict__ h2)
{
    const int bid = blockIdx.x;
    const int seg = bid & (SEG-1);
    const int dir = (bid >> 5) & 1;
    const int b   = bid >> 6;
    const int j   = threadIdx.x;            // 0..127
    const int blk = (b*2+dir)*SEG + seg;
    const size_t segIdx = (size_t)blk*HDIM + j;   // channel j; +128 for hi channel

    const float2* Td2 = (const float2*)T + (size_t)dir*VOCABN*HDIM;
    const float2* Ud2 = (const float2*)U + (size_t)dir*8*HDIM;
    float2 uLo0=Ud2[0*HDIM+j],     uLo1=Ud2[1*HDIM+j],     uLo2=Ud2[2*HDIM+j],
           uLo3=Ud2[3*HDIM+j],     uLo4=Ud2[4*HDIM+j],     uLo5=Ud2[5*HDIM+j],
           uLo6=Ud2[6*HDIM+j];
    float2 uHi0=Ud2[0*HDIM+j+128], uHi1=Ud2[1*HDIM+j+128], uHi2=Ud2[2*HDIM+j+128],
           uHi3=Ud2[3*HDIM+j+128], uHi4=Ud2[4*HDIM+j+128], uHi5=Ud2[5*HDIM+j+128],
           uHi6=Ud2[6*HDIM+j+128];
    const float muLo = (MODE==1 || MODE==3) ? Mu[dir*HDIM + j]       : 0.f;
    const float muHi = (MODE==1 || MODE==3) ? Mu[dir*HDIM + j + 128] : 0.f;

    const int sBeg = seg*SEGLEN;
    const int r0   = b*SN + (dir ? (SN-1-sBeg) : sBeg);
    const int dstep= dir ? -1 : 1;

    // launder a zero through asm so X addresses look divergent -> vector loads (vmcnt)
    int zv = 0;
    asm("" : "+v"(zv));
    const float* xrBase = Xp + (size_t)r0*8 + zv;
    const float* wbv    = w + (size_t)b*SN + sBeg + zv;   // MODE2 weights (uniform vector loads)
    const char* Tb = (const char*)Td2;
    const int j8 = j*8;

    #define XROWP(si) (xrBase + (ptrdiff_t)(dstep*(si))*8)
    #define EVOF(r)   __float_as_int((r).p6e.y)

    // prologue: X ring depth 4, T ring depth 2 (both channels)
    XRow x0 = loadRow(XROWP(0));
    XRow x1 = loadRow(XROWP(1));
    XRow x2 = loadRow(XROWP(2));
    XRow x3 = loadRow(XROWP(3));
    const char* tp0 = Tb + (uint32_t)(EVOF(x0) + j8);
    const char* tp1 = Tb + (uint32_t)(EVOF(x1) + j8);
    float2 tLo0 = *(const float2*)tp0;
    float2 tHi0 = *(const float2*)(tp0 + 1024);
    float2 tLo1 = *(const float2*)tp1;
    float2 tHi1 = *(const float2*)(tp1 + 1024);

    float hLo = (MODE==0) ? 0.f : hstart[segIdx];
    float hHi = (MODE==0) ? 0.f : hstart[segIdx + 128];
    float aaccLo = 1.f, aaccHi = 1.f;
    float ctxLo = 0.f, ctxHi = 0.f;
    float hpLo = 0.f, hpHi = 0.f;
    float* swpp = swp + (size_t)(b*4 + dir*2 + (j>>6))*SN + sBeg;
    uint32_t* h2p = h2 + (size_t)blk*(SEGLEN/2)*HDIM + j;

    #pragma unroll 4
    for (int si=0; si<SEGLEN; ++si){
        // issue X vector load for si+4 and T loads for si+2 (register rings)
        const int i4 = (si+4 < SEGLEN) ? si+4 : SEGLEN-1;
        const XRow x4 = loadRow(XROWP(i4));
        const char* tp2 = Tb + (uint32_t)(EVOF(x2) + j8);
        const float2 tLo2 = *(const float2*)tp2;
        const float2 tHi2 = *(const float2*)(tp2 + 1024);

        float2 zfLo = tLo0, zfHi = tHi0;
        zfLo = pk_fma_blo(x0.p01, uLo0, zfLo);  zfHi = pk_fma_blo(x0.p01, uHi0, zfHi);  // n0
        zfLo = pk_fma_bhi(x0.p01, uLo1, zfLo);  zfHi = pk_fma_bhi(x0.p01, uHi1, zfHi);  // n1
        zfLo = pk_fma_blo(x0.p23, uLo2, zfLo);  zfHi = pk_fma_blo(x0.p23, uHi2, zfHi);  // n2
        zfLo = pk_fma_bhi(x0.p23, uLo3, zfLo);  zfHi = pk_fma_bhi(x0.p23, uHi3, zfHi);  // n3
        zfLo = pk_fma_blo(x0.p45, uLo4, zfLo);  zfHi = pk_fma_blo(x0.p45, uHi4, zfHi);  // n4
        zfLo = pk_fma_bhi(x0.p45, uLo5, zfLo);  zfHi = pk_fma_bhi(x0.p45, uHi5, zfHi);  // n5
        zfLo = pk_fma_blo(x0.p6e, uLo6, zfLo);  zfHi = pk_fma_blo(x0.p6e, uHi6, zfHi);  // n6

        // gates, one reciprocal per channel (zf pre-scaled by CZ/CF)
        const float e2zL = fast_exp2(zfLo.x), efL = fast_exp2(zfLo.y);
        const float e2zH = fast_exp2(zfHi.x), efH = fast_exp2(zfHi.y);
        const float a2L = 1.f + e2zL, a1L = 1.f + efL;
        const float a2H = 1.f + e2zH, a1H = 1.f + efH;
        const float rL = rcpf(a1L * a2L);
        const float rH = rcpf(a1H * a2H);
        hLo = fmaf(efL * hLo, a2L, e2zL - 1.f) * rL;
        hHi = fmaf(efH * hHi, a2H, e2zH - 1.f) * rH;

        if (MODE==0){
            aaccLo *= efL * a2L * rL;            // f = ef/(1+ef)
            aaccHi *= efH * a2H * rH;
        } else if (MODE==1 || MODE==3){
            float pr = waveRedDpp(fmaf(hHi, muHi, hLo * muLo));
            if ((j & 63) == 63) swpp[si] = pr;
            if (MODE==1){
                if (si & 1){
                    h2p[0]   = cvt_pk_bf16(hpLo, hLo);
                    h2p[128] = cvt_pk_bf16(hpHi, hHi);
                    h2p += HDIM;
                } else { hpLo = hLo; hpHi = hHi; }
            }
        } else {
            const float ws_ = wbv[si];
            ctxLo = fmaf(ws_, hLo, ctxLo);
            ctxHi = fmaf(ws_, hHi, ctxHi);
        }
        // rotate rings (register renaming under unroll)
        x0=x1; x1=x2; x2=x3; x3=x4;
        tLo0=tLo1; tHi0=tHi1; tLo1=tLo2; tHi1=tHi2;
    }
    #undef XROWP
    #undef EVOF
    if (MODE==0){
        aArr[segIdx] = aaccLo; aArr[segIdx+128] = aaccHi;
        cArr[segIdx] = hLo;    cArr[segIdx+128] = hHi;
    }
    if (MODE==2){ ctxp[segIdx] = ctxLo; ctxp[segIdx+128] = ctxHi; }
}

// ---------------- compose: hstart[seg] = h; h = a*h + c ----------------
__global__ __launch_bounds__(256) void k_compose(const float* __restrict__ aArr, const float* __restrict__ cArr,
                                                 float* __restrict__ hstart)
{
    const int bd = blockIdx.x;   // b*2 + dir
    const int j  = threadIdx.x;
    float h = 0.f;
    #pragma unroll
    for (int seg=0; seg<SEG; ++seg){
        const size_t idx = ((size_t)bd*SEG + seg)*HDIM + j;
        hstart[idx] = h;
        h = fmaf(aArr[idx], h, cArr[idx]);
    }
}

// ---------------- K3: softmax over S per batch (4 partial rows per b) ----------------
__global__ __launch_bounds__(256) void k3_softmax(const float* __restrict__ swp, float* __restrict__ w)
{
    __shared__ float sc[SN];
    __shared__ float red[4];
    const int b = blockIdx.x, t = threadIdx.x;
    for (int s=t; s<SN; s+=256){
        float acc = 0.f;
        #pragma unroll
        for (int r=0;r<4;++r) acc += swp[((size_t)b*4 + r)*SN + s];
        sc[s] = acc;
    }
    __syncthreads();
    float m = -3.4e38f;
    for (int s=t; s<SN; s+=256) m = fmaxf(m, sc[s]);
    #pragma unroll
    for (int o=32;o;o>>=1) m = fmaxf(m, __shfl_xor(m,o,64));
    if ((t&63)==0) red[t>>6] = m;
    __syncthreads();
    m = fmaxf(fmaxf(red[0],red[1]), fmaxf(red[2],red[3]));
    float zs = 0.f;
    for (int s=t; s<SN; s+=256){
        float e = __expf(sc[s]-m);
        sc[s] = e;
        zs += e;
    }
    #pragma unroll
    for (int o=32;o;o>>=1) zs += __shfl_xor(zs,o,64);
    __syncthreads();
    if ((t&63)==0) red[t>>6] = zs;
    __syncthreads();
    zs = red[0]+red[1]+red[2]+red[3];
    float invz = rcpf(zs);
    for (int s=t; s<SN; s+=256) w[(size_t)b*SN + s] = sc[s]*invz;
}

// ---------------- K4: ctx from stored bf16 h (memory-bound replay) ----------------
__global__ __launch_bounds__(256) void k4_ctx(const uint32_t* __restrict__ h2, const float* __restrict__ w,
                                              float* __restrict__ ctxp)
{
    const int bid = blockIdx.x;
    const int seg = bid & (SEG-1);
    const int dir = (bid >> 5) & 1;
    const int b   = bid >> 6;
    const int blk = (b*2+dir)*SEG + seg;
    const int j   = threadIdx.x;
    const float* wb = w + (size_t)b*SN + seg*SEGLEN;
    const uint32_t* hp = h2 + (size_t)blk*(SEGLEN/2)*HDIM + j;
    float acc = 0.f;
    #pragma unroll 8
    for (int si2=0; si2<SEGLEN/2; ++si2){
        const uint32_t pk = hp[(size_t)si2*HDIM];
        const float hlo = __int_as_float(pk << 16);
        const float hhi = __int_as_float(pk & 0xffff0000u);
        acc = fmaf(wb[2*si2  ], hlo, acc);
        acc = fmaf(wb[2*si2+1], hhi, acc);
    }
    ctxp[(size_t)blk*HDIM + j] = acc;
}

// ---------------- K5: out[b] = (sum_seg ctxp) . out_W + out_b ----------------
__global__ __launch_bounds__(512) void k5_out(const float* __restrict__ ctxp, const float* __restrict__ out_W,
                                              const float* __restrict__ out_b, float* __restrict__ out)
{
    __shared__ float red[8];
    const int b = blockIdx.x, c = threadIdx.x;
    const int dir = c >> 8, j = c & (HDIM-1);
    float acc = 0.f;
    #pragma unroll
    for (int seg=0; seg<SEG; ++seg)
        acc += ctxp[((size_t)(b*2+dir)*SEG + seg)*HDIM + j];
    float p = acc * out_W[c];
    #pragma unroll
    for (int o=32;o;o>>=1) p += __shfl_xor(p,o,64);
    if ((c&63)==0) red[c>>6] = p;
    __syncthreads();
    if (c==0){
        float t = 0.f;
        #pragma unroll
        for (int r=0;r<8;++r) t += red[r];
        out[b] = t + out_b[0];
    }
}

extern "C" void kernel_launch(void* const* d_in, const int* in_sizes, int n_in,
                              void* d_out, int out_size, void* d_ws, size_t ws_size,
                              hipStream_t stream)
{
    const float* X     = (const float*)d_in[0];
    const float* emb   = (const float*)d_in[1];
    const float* num_W = (const float*)d_in[2];
    const float* num_b = (const float*)d_in[3];
    const float* Wf    = (const float*)d_in[4];
    const float* bf    = (const float*)d_in[5];
    const float* Wb    = (const float*)d_in[6];
    const float* bb    = (const float*)d_in[7];
    const float* Mu    = (const float*)d_in[8];
    const float* out_W = (const float*)d_in[9];
    const float* out_b = (const float*)d_in[10];
    float* out = (float*)d_out;

    float* ws = (float*)d_ws;
    size_t off = 0;
    float* swp   = ws + off; off += (size_t)BN*4*SN;           // 2 MB (4 partial rows per b)
    float* w     = ws + off; off += (size_t)BN*SN;             // 0.5 MB
    float* T     = ws + off; off += (size_t)2*VOCABN*TWOH;     // interleaved, pre-scaled
    float* U     = ws + off; off += (size_t)2*8*TWOH;          // interleaved, pre-scaled
    float* aArr  = ws + off; off += (size_t)BN*2*SEG*HDIM;     // 4 MB
    float* cArr  = ws + off; off += (size_t)BN*2*SEG*HDIM;     // 4 MB
    float* hstart= ws + off; off += (size_t)BN*2*SEG*HDIM;     // 4 MB
    float* ctxp  = ws + off; off += (size_t)BN*2*SEG*HDIM;     // 4 MB
    float* Xp    = ws + off; off += (size_t)BN*SN*8;           // 4 MB prepacked X
    uint32_t* h2 = (uint32_t*)(ws + off);
    off += (size_t)BN*2*SEG*(SEGLEN/2)*HDIM;                   // 128 MB packed bf16 h
    const bool useStore = ((size_t)off * sizeof(float)) <= ws_size;

    hipLaunchKernelGGL(k0_prep,     dim3(BN*SN/256),   dim3(256), 0, stream, X, Xp);
    hipLaunchKernelGGL(k1_tables,   dim3(2*VOCABN+2),  dim3(512), 0, stream,
                       emb, num_W, num_b, Wf, bf, Wb, bb, T, U);
    hipLaunchKernelGGL(k2_scan<0>,  dim3(BN*2*SEG),    dim3(128), 0, stream,
                       Xp, T, U, Mu, w, hstart, aArr, cArr, swp, ctxp, h2);
    hipLaunchKernelGGL(k_compose,   dim3(BN*2),        dim3(256), 0, stream,
                       aArr, cArr, hstart);
    if (useStore) {
        hipLaunchKernelGGL(k2_scan<1>, dim3(BN*2*SEG), dim3(128), 0, stream,
                           Xp, T, U, Mu, w, hstart, aArr, cArr, swp, ctxp, h2);
        hipLaunchKernelGGL(k3_softmax, dim3(BN),       dim3(256), 0, stream, swp, w);
        hipLaunchKernelGGL(k4_ctx,     dim3(BN*2*SEG), dim3(256), 0, stream, h2, w, ctxp);
    } else {
        hipLaunchKernelGGL(k2_scan<3>, dim3(BN*2*SEG), dim3(128), 0, stream,
                           Xp, T, U, Mu, w, hstart, aArr, cArr, swp, ctxp, h2);
        hipLaunchKernelGGL(k3_softmax, dim3(BN),       dim3(256), 0, stream, swp, w);
        hipLaunchKernelGGL(k2_scan<2>, dim3(BN*2*SEG), dim3(128), 0, stream,
                           Xp, T, U, Mu, w, hstart, aArr, cArr, swp, ctxp, h2);
    }
    hipLaunchKernelGGL(k5_out,      dim3(BN),          dim3(512), 0, stream,
                       ctxp, out_W, out_b, out);
}

// Round 11
// 164.083 us; speedup vs baseline: 1.3124x; 1.3124x over previous
//
#include <hip/hip_runtime.h>
#include <stdint.h>

#define VOCABN 64
#define EMBN   128
#define HDIM   256
#define NUMIN  7
#define BN     64
#define SN     2048
#define TWOH   512
#define SEG    32
#define SEGLEN 64

#define CZ 2.8853900818f   // 2*log2(e)
#define CF 1.4426950409f   // log2(e)

__device__ __forceinline__ float rcpf(float x){ return __builtin_amdgcn_rcpf(x); }

__device__ __forceinline__ float fast_exp2(float x){
#if __has_builtin(__builtin_amdgcn_exp2f)
    return __builtin_amdgcn_exp2f(x);
#else
    return exp2f(x);
#endif
}

// v_pk_fma_f32 with src0 = SGPR pair, broadcasting its LO word to both lanes of the result
__device__ __forceinline__ float2 pk_fma_s_lo(uint64_t a, float2 b, float2 c){
    float2 d;
    asm("v_pk_fma_f32 %0, %1, %2, %3 op_sel_hi:[0,1,1]" : "=v"(d) : "s"(a), "v"(b), "v"(c));
    return d;
}
// v_pk_fma_f32 with src0 = SGPR pair, broadcasting its HI word
__device__ __forceinline__ float2 pk_fma_s_hi(uint64_t a, float2 b, float2 c){
    float2 d;
    asm("v_pk_fma_f32 %0, %1, %2, %3 op_sel:[1,0,0] op_sel_hi:[1,1,1]" : "=v"(d) : "s"(a), "v"(b), "v"(c));
    return d;
}

// pack two f32 -> two bf16 (RNE) in one dword: lo16 = bf16(a), hi16 = bf16(b)
__device__ __forceinline__ uint32_t cvt_pk_bf16(float a, float b){
    uint32_t r;
    asm("v_cvt_pk_bf16_f32 %0, %1, %2" : "=v"(r) : "v"(a), "v"(b));
    return r;
}

// 64-lane sum via DPP; result valid in lane 63.
__device__ __forceinline__ float waveRedDpp(float x){
    x += __int_as_float(__builtin_amdgcn_update_dpp(0, __float_as_int(x), 0x111, 0xf, 0xf, false)); // row_shr:1
    x += __int_as_float(__builtin_amdgcn_update_dpp(0, __float_as_int(x), 0x112, 0xf, 0xf, false)); // row_shr:2
    x += __int_as_float(__builtin_amdgcn_update_dpp(0, __float_as_int(x), 0x114, 0xf, 0xf, false)); // row_shr:4
    x += __int_as_float(__builtin_amdgcn_update_dpp(0, __float_as_int(x), 0x118, 0xf, 0xf, false)); // row_shr:8
    x += __int_as_float(__builtin_amdgcn_update_dpp(0, __float_as_int(x), 0x142, 0xa, 0xf, false)); // row_bcast:15
    x += __int_as_float(__builtin_amdgcn_update_dpp(0, __float_as_int(x), 0x143, 0xc, 0xf, false)); // row_bcast:31
    return x;
}

// ---------------- K0: prepack X rows for scalar loads ----------------
// X'[row] = [n0 n1 n2 n3 n4 n5 n6 evByteOffsetBits]
__global__ __launch_bounds__(256) void k0_prep(const float* __restrict__ X, float* __restrict__ Xp)
{
    const int r = blockIdx.x*256 + threadIdx.x;     // r < BN*SN
    const float4* src = (const float4*)(X + (size_t)r*8);
    const float4 a = src[0], b4 = src[1];
    float4* dst = (float4*)(Xp + (size_t)r*8);
    dst[0] = make_float4(a.y, a.z, a.w, b4.x);
    dst[1] = make_float4(b4.y, b4.z, b4.w, __int_as_float((int)a.x * (HDIM*8)));
}

// ---------------- K1: fold emb/bias/num path into INTERLEAVED, PRE-SCALED tables ----------------
// T[(dir,v,j)] = float2(CZ*z-col j, CF*f-col j); U likewise (so exp2 applies directly).
__global__ __launch_bounds__(512) void k1_tables(
    const float* __restrict__ emb, const float* __restrict__ num_W, const float* __restrict__ num_b,
    const float* __restrict__ Wf, const float* __restrict__ bf,
    const float* __restrict__ Wb, const float* __restrict__ bb,
    float* __restrict__ T, float* __restrict__ U)
{
    const int blk = blockIdx.x;
    const int c = threadIdx.x;
    const int j = c & (HDIM-1);
    const int g = c >> 8;               // 0 -> z gate, 1 -> f gate
    const int col = g*HDIM + j;
    const float gs = g ? CF : CZ;
    if (blk < 2*VOCABN) {
        const int dir = blk & 1, v = blk >> 1;
        const float* W    = dir ? Wb : Wf;
        const float* bias = dir ? bb : bf;
        float acc = bias[col];
        const float* e = emb + (size_t)v*EMBN;
        #pragma unroll 8
        for (int k=0;k<EMBN;++k) acc = fmaf(e[k], W[(size_t)k*768 + col], acc);
        #pragma unroll
        for (int m=0;m<4;++m)    acc = fmaf(num_b[m], W[(size_t)(EMBN+m)*768 + col], acc);
        T[(((size_t)dir*VOCABN + v)*HDIM + j)*2 + g] = acc * gs;
    } else {
        const int dir = blk - 2*VOCABN;
        const float* W = dir ? Wb : Wf;
        #pragma unroll
        for (int i=0;i<NUMIN;++i){
            float acc = 0.f;
            #pragma unroll
            for (int m=0;m<4;++m) acc = fmaf(num_W[i*4+m], W[(size_t)(EMBN+m)*768 + col], acc);
            U[(((size_t)dir*8 + i)*HDIM + j)*2 + g] = acc * gs;
        }
    }
}

// ---------------- K2: segmented fo-pool scan, 2 channels/thread ----------------
// MODE 0: per-segment affine coefficients a=prod(f), c=scan from 0.
// MODE 1: scan from hstart, score partials via DPP reduce, AND store h as packed bf16.
// MODE 2: scan from hstart, ctx += w[s]*h (recompute fallback, no h storage).
// MODE 3: scan from hstart, score partials only (fallback when h2 doesn't fit ws).
// Block=(b,dir,seg) with 128 threads; thread j owns channels j and j+128.
// X rows: depth-4 SGPR ring (scalar loads); T rows: depth-2 register ring, both
// channels' loads share one scalar base (saddr) with +1KB immediate.
// SEG=32 -> 8192 waves = 8/SIMD nominal: per-wave lgkm drain stalls hidden by TLP.
template<int MODE>
__global__ __launch_bounds__(128) void k2_scan(
    const float* __restrict__ Xp, const float* __restrict__ T, const float* __restrict__ U,
    const float* __restrict__ Mu, const float* __restrict__ w,
    const float* __restrict__ hstart,
    float* __restrict__ aArr, float* __restrict__ cArr,
    float* __restrict__ swp, float* __restrict__ ctxp, uint32_t* __restrict__ h2)
{
    const int bid = blockIdx.x;
    const int seg = bid & (SEG-1);
    const int dir = (bid >> 5) & 1;
    const int b   = bid >> 6;
    const int j   = threadIdx.x;            // 0..127
    const int blk = (b*2+dir)*SEG + seg;
    const size_t segIdx = (size_t)blk*HDIM + j;   // channel j; +128 for hi channel

    const float2* Td2 = (const float2*)T + (size_t)dir*VOCABN*HDIM;
    const float2* Ud2 = (const float2*)U + (size_t)dir*8*HDIM;
    float2 uLo0=Ud2[0*HDIM+j],     uLo1=Ud2[1*HDIM+j],     uLo2=Ud2[2*HDIM+j],
           uLo3=Ud2[3*HDIM+j],     uLo4=Ud2[4*HDIM+j],     uLo5=Ud2[5*HDIM+j],
           uLo6=Ud2[6*HDIM+j];
    float2 uHi0=Ud2[0*HDIM+j+128], uHi1=Ud2[1*HDIM+j+128], uHi2=Ud2[2*HDIM+j+128],
           uHi3=Ud2[3*HDIM+j+128], uHi4=Ud2[4*HDIM+j+128], uHi5=Ud2[5*HDIM+j+128],
           uHi6=Ud2[6*HDIM+j+128];
    const float muLo = (MODE==1 || MODE==3) ? Mu[dir*HDIM + j]       : 0.f;
    const float muHi = (MODE==1 || MODE==3) ? Mu[dir*HDIM + j + 128] : 0.f;

    const int sBeg = seg*SEGLEN;
    const int r0   = b*SN + (dir ? (SN-1-sBeg) : sBeg);
    const int dstep= dir ? -1 : 1;
    const uint64_t* xq = (const uint64_t*)Xp;      // 4 qwords per row
    const float* wb = w + (size_t)b*SN + sBeg;     // MODE2 weights (uniform loads)
    const char* Tb = (const char*)Td2;
    const int j8 = j*8;

    #define ROWQ(si,k) (xq[(size_t)(r0 + dstep*(si))*4 + (k)])
    #define TROW(q)    (Tb + (int)((q)>>32))

    // prologue: X ring depth 4, T ring depth 2 (both channels)
    uint64_t qa0=ROWQ(0,0), qa1=ROWQ(0,1), qa2=ROWQ(0,2), qa3=ROWQ(0,3);
    uint64_t qb0=ROWQ(1,0), qb1=ROWQ(1,1), qb2=ROWQ(1,2), qb3=ROWQ(1,3);
    uint64_t qc0=ROWQ(2,0), qc1=ROWQ(2,1), qc2=ROWQ(2,2), qc3=ROWQ(2,3);
    uint64_t qd0=ROWQ(3,0), qd1=ROWQ(3,1), qd2=ROWQ(3,2), qd3=ROWQ(3,3);
    const char* tp0 = TROW(qa3);
    const char* tp1 = TROW(qb3);
    float2 tLo0 = *(const float2*)(tp0 + j8);
    float2 tHi0 = *(const float2*)(tp0 + j8 + 1024);
    float2 tLo1 = *(const float2*)(tp1 + j8);
    float2 tHi1 = *(const float2*)(tp1 + j8 + 1024);

    float hLo = (MODE==0) ? 0.f : hstart[segIdx];
    float hHi = (MODE==0) ? 0.f : hstart[segIdx + 128];
    float aaccLo = 1.f, aaccHi = 1.f;
    float ctxLo = 0.f, ctxHi = 0.f;
    float hpLo = 0.f, hpHi = 0.f;
    float* swpp = swp + (size_t)(b*4 + dir*2 + (j>>6))*SN + sBeg;
    uint32_t* h2p = h2 + (size_t)blk*(SEGLEN/2)*HDIM + j;

    #pragma unroll 4
    for (int si=0; si<SEGLEN; ++si){
        // issue X scalar loads for si+4 (2-iter slack before use as T base, 4 before math)
        const int i4 = (si+4 < SEGLEN) ? si+4 : SEGLEN-1;
        const uint64_t qe0=ROWQ(i4,0), qe1=ROWQ(i4,1), qe2=ROWQ(i4,2), qe3=ROWQ(i4,3);
        // issue T loads for si+2 (base from qc, loaded 2 iterations ago)
        const char* tp2 = TROW(qc3);
        const float2 tLo2 = *(const float2*)(tp2 + j8);
        const float2 tHi2 = *(const float2*)(tp2 + j8 + 1024);

        float2 zfLo = tLo0, zfHi = tHi0;
        zfLo = pk_fma_s_lo(qa0, uLo0, zfLo);  zfHi = pk_fma_s_lo(qa0, uHi0, zfHi);  // n0
        zfLo = pk_fma_s_hi(qa0, uLo1, zfLo);  zfHi = pk_fma_s_hi(qa0, uHi1, zfHi);  // n1
        zfLo = pk_fma_s_lo(qa1, uLo2, zfLo);  zfHi = pk_fma_s_lo(qa1, uHi2, zfHi);  // n2
        zfLo = pk_fma_s_hi(qa1, uLo3, zfLo);  zfHi = pk_fma_s_hi(qa1, uHi3, zfHi);  // n3
        zfLo = pk_fma_s_lo(qa2, uLo4, zfLo);  zfHi = pk_fma_s_lo(qa2, uHi4, zfHi);  // n4
        zfLo = pk_fma_s_hi(qa2, uLo5, zfLo);  zfHi = pk_fma_s_hi(qa2, uHi5, zfHi);  // n5
        zfLo = pk_fma_s_lo(qa3, uLo6, zfLo);  zfHi = pk_fma_s_lo(qa3, uHi6, zfHi);  // n6

        // gates, one reciprocal per channel (zf pre-scaled by CZ/CF)
        const float e2zL = fast_exp2(zfLo.x), efL = fast_exp2(zfLo.y);
        const float e2zH = fast_exp2(zfHi.x), efH = fast_exp2(zfHi.y);
        const float a2L = 1.f + e2zL, a1L = 1.f + efL;
        const float a2H = 1.f + e2zH, a1H = 1.f + efH;
        const float rL = rcpf(a1L * a2L);
        const float rH = rcpf(a1H * a2H);
        hLo = fmaf(efL * hLo, a2L, e2zL - 1.f) * rL;
        hHi = fmaf(efH * hHi, a2H, e2zH - 1.f) * rH;

        if (MODE==0){
            aaccLo *= efL * a2L * rL;            // f = ef/(1+ef)
            aaccHi *= efH * a2H * rH;
        } else if (MODE==1 || MODE==3){
            float pr = waveRedDpp(fmaf(hHi, muHi, hLo * muLo));
            if ((j & 63) == 63) swpp[si] = pr;
            if (MODE==1){
                if (si & 1){
                    h2p[0]   = cvt_pk_bf16(hpLo, hLo);
                    h2p[128] = cvt_pk_bf16(hpHi, hHi);
                    h2p += HDIM;
                } else { hpLo = hLo; hpHi = hHi; }
            }
        } else {
            const float ws_ = wb[si];
            ctxLo = fmaf(ws_, hLo, ctxLo);
            ctxHi = fmaf(ws_, hHi, ctxHi);
        }
        // rotate rings
        qa0=qb0; qa1=qb1; qa2=qb2; qa3=qb3;
        qb0=qc0; qb1=qc1; qb2=qc2; qb3=qc3;
        qc0=qd0; qc1=qd1; qc2=qd2; qc3=qd3;
        qd0=qe0; qd1=qe1; qd2=qe2; qd3=qe3;
        tLo0=tLo1; tHi0=tHi1; tLo1=tLo2; tHi1=tHi2;
    }
    #undef ROWQ
    #undef TROW
    if (MODE==0){
        aArr[segIdx] = aaccLo; aArr[segIdx+128] = aaccHi;
        cArr[segIdx] = hLo;    cArr[segIdx+128] = hHi;
    }
    if (MODE==2){ ctxp[segIdx] = ctxLo; ctxp[segIdx+128] = ctxHi; }
}

// ---------------- compose: hstart[seg] = h; h = a*h + c ----------------
__global__ __launch_bounds__(256) void k_compose(const float* __restrict__ aArr, const float* __restrict__ cArr,
                                                 float* __restrict__ hstart)
{
    const int bd = blockIdx.x;   // b*2 + dir
    const int j  = threadIdx.x;
    float h = 0.f;
    #pragma unroll
    for (int seg=0; seg<SEG; ++seg){
        const size_t idx = ((size_t)bd*SEG + seg)*HDIM + j;
        hstart[idx] = h;
        h = fmaf(aArr[idx], h, cArr[idx]);
    }
}

// ---------------- K3: softmax over S per batch (4 partial rows per b) ----------------
__global__ __launch_bounds__(256) void k3_softmax(const float* __restrict__ swp, float* __restrict__ w)
{
    __shared__ float sc[SN];
    __shared__ float red[4];
    const int b = blockIdx.x, t = threadIdx.x;
    for (int s=t; s<SN; s+=256){
        float acc = 0.f;
        #pragma unroll
        for (int r=0;r<4;++r) acc += swp[((size_t)b*4 + r)*SN + s];
        sc[s] = acc;
    }
    __syncthreads();
    float m = -3.4e38f;
    for (int s=t; s<SN; s+=256) m = fmaxf(m, sc[s]);
    #pragma unroll
    for (int o=32;o;o>>=1) m = fmaxf(m, __shfl_xor(m,o,64));
    if ((t&63)==0) red[t>>6] = m;
    __syncthreads();
    m = fmaxf(fmaxf(red[0],red[1]), fmaxf(red[2],red[3]));
    float zs = 0.f;
    for (int s=t; s<SN; s+=256){
        float e = __expf(sc[s]-m);
        sc[s] = e;
        zs += e;
    }
    #pragma unroll
    for (int o=32;o;o>>=1) zs += __shfl_xor(zs,o,64);
    __syncthreads();
    if ((t&63)==0) red[t>>6] = zs;
    __syncthreads();
    zs = red[0]+red[1]+red[2]+red[3];
    float invz = rcpf(zs);
    for (int s=t; s<SN; s+=256) w[(size_t)b*SN + s] = sc[s]*invz;
}

// ---------------- K4: ctx from stored bf16 h (memory-bound replay) ----------------
__global__ __launch_bounds__(256) void k4_ctx(const uint32_t* __restrict__ h2, const float* __restrict__ w,
                                              float* __restrict__ ctxp)
{
    const int bid = blockIdx.x;
    const int seg = bid & (SEG-1);
    const int dir = (bid >> 5) & 1;
    const int b   = bid >> 6;
    const int blk = (b*2+dir)*SEG + seg;
    const int j   = threadIdx.x;
    const float* wb = w + (size_t)b*SN + seg*SEGLEN;
    const uint32_t* hp = h2 + (size_t)blk*(SEGLEN/2)*HDIM + j;
    float acc = 0.f;
    #pragma unroll 8
    for (int si2=0; si2<SEGLEN/2; ++si2){
        const uint32_t pk = hp[(size_t)si2*HDIM];
        const float hlo = __int_as_float(pk << 16);
        const float hhi = __int_as_float(pk & 0xffff0000u);
        acc = fmaf(wb[2*si2  ], hlo, acc);
        acc = fmaf(wb[2*si2+1], hhi, acc);
    }
    ctxp[(size_t)blk*HDIM + j] = acc;
}

// ---------------- K5: out[b] = (sum_seg ctxp) . out_W + out_b ----------------
__global__ __launch_bounds__(512) void k5_out(const float* __restrict__ ctxp, const float* __restrict__ out_W,
                                              const float* __restrict__ out_b, float* __restrict__ out)
{
    __shared__ float red[8];
    const int b = blockIdx.x, c = threadIdx.x;
    const int dir = c >> 8, j = c & (HDIM-1);
    float acc = 0.f;
    #pragma unroll
    for (int seg=0; seg<SEG; ++seg)
        acc += ctxp[((size_t)(b*2+dir)*SEG + seg)*HDIM + j];
    float p = acc * out_W[c];
    #pragma unroll
    for (int o=32;o;o>>=1) p += __shfl_xor(p,o,64);
    if ((c&63)==0) red[c>>6] = p;
    __syncthreads();
    if (c==0){
        float t = 0.f;
        #pragma unroll
        for (int r=0;r<8;++r) t += red[r];
        out[b] = t + out_b[0];
    }
}

extern "C" void kernel_launch(void* const* d_in, const int* in_sizes, int n_in,
                              void* d_out, int out_size, void* d_ws, size_t ws_size,
                              hipStream_t stream)
{
    const float* X     = (const float*)d_in[0];
    const float* emb   = (const float*)d_in[1];
    const float* num_W = (const float*)d_in[2];
    const float* num_b = (const float*)d_in[3];
    const float* Wf    = (const float*)d_in[4];
    const float* bf    = (const float*)d_in[5];
    const float* Wb    = (const float*)d_in[6];
    const float* bb    = (const float*)d_in[7];
    const float* Mu    = (const float*)d_in[8];
    const float* out_W = (const float*)d_in[9];
    const float* out_b = (const float*)d_in[10];
    float* out = (float*)d_out;

    float* ws = (float*)d_ws;
    size_t off = 0;
    float* swp   = ws + off; off += (size_t)BN*4*SN;           // 2 MB (4 partial rows per b)
    float* w     = ws + off; off += (size_t)BN*SN;             // 0.5 MB
    float* T     = ws + off; off += (size_t)2*VOCABN*TWOH;     // interleaved, pre-scaled
    float* U     = ws + off; off += (size_t)2*8*TWOH;          // interleaved, pre-scaled
    float* aArr  = ws + off; off += (size_t)BN*2*SEG*HDIM;     // 4 MB
    float* cArr  = ws + off; off += (size_t)BN*2*SEG*HDIM;     // 4 MB
    float* hstart= ws + off; off += (size_t)BN*2*SEG*HDIM;     // 4 MB
    float* ctxp  = ws + off; off += (size_t)BN*2*SEG*HDIM;     // 4 MB
    float* Xp    = ws + off; off += (size_t)BN*SN*8;           // 4 MB prepacked X
    uint32_t* h2 = (uint32_t*)(ws + off);
    off += (size_t)BN*2*SEG*(SEGLEN/2)*HDIM;                   // 128 MB packed bf16 h
    const bool useStore = ((size_t)off * sizeof(float)) <= ws_size;

    hipLaunchKernelGGL(k0_prep,     dim3(BN*SN/256),   dim3(256), 0, stream, X, Xp);
    hipLaunchKernelGGL(k1_tables,   dim3(2*VOCABN+2),  dim3(512), 0, stream,
                       emb, num_W, num_b, Wf, bf, Wb, bb, T, U);
    hipLaunchKernelGGL(k2_scan<0>,  dim3(BN*2*SEG),    dim3(128), 0, stream,
                       Xp, T, U, Mu, w, hstart, aArr, cArr, swp, ctxp, h2);
    hipLaunchKernelGGL(k_compose,   dim3(BN*2),        dim3(256), 0, stream,
                       aArr, cArr, hstart);
    if (useStore) {
        hipLaunchKernelGGL(k2_scan<1>, dim3(BN*2*SEG), dim3(128), 0, stream,
                           Xp, T, U, Mu, w, hstart, aArr, cArr, swp, ctxp, h2);
        hipLaunchKernelGGL(k3_softmax, dim3(BN),       dim3(256), 0, stream, swp, w);
        hipLaunchKernelGGL(k4_ctx,     dim3(BN*2*SEG), dim3(256), 0, stream, h2, w, ctxp);
    } else {
        hipLaunchKernelGGL(k2_scan<3>, dim3(BN*2*SEG), dim3(128), 0, stream,
                           Xp, T, U, Mu, w, hstart, aArr, cArr, swp, ctxp, h2);
        hipLaunchKernelGGL(k3_softmax, dim3(BN),       dim3(256), 0, stream, swp, w);
        hipLaunchKernelGGL(k2_scan<2>, dim3(BN*2*SEG), dim3(128), 0, stream,
                           Xp, T, U, Mu, w, hstart, aArr, cArr, swp, ctxp, h2);
    }
    hipLaunchKernelGGL(k5_out,      dim3(BN),          dim3(512), 0, stream,
                       ctxp, out_W, out_b, out);
}

// Round 14
// 159.615 us; speedup vs baseline: 1.3491x; 1.0280x over previous
//
#include <hip/hip_runtime.h>
#include <stdint.h>

#define VOCABN 64
#define EMBN   128
#define HDIM   256
#define NUMIN  7
#define BN     64
#define SN     2048
#define TWOH   512
#define SEG    32
#define SEGLEN 64

#define CZ 2.8853900818f   // 2*log2(e)
#define CF 1.4426950409f   // log2(e)

__device__ __forceinline__ float rcpf(float x){ return __builtin_amdgcn_rcpf(x); }

__device__ __forceinline__ float fast_exp2(float x){
#if __has_builtin(__builtin_amdgcn_exp2f)
    return __builtin_amdgcn_exp2f(x);
#else
    return exp2f(x);
#endif
}

// v_pk_fma_f32 with src0 broadcast from LO half (both result lanes use src0.lo)
__device__ __forceinline__ float2 pk_fma_blo(float2 a, float2 b, float2 c){
    float2 d;
    asm("v_pk_fma_f32 %0, %1, %2, %3 op_sel_hi:[0,1,1]" : "=v"(d) : "v"(a), "v"(b), "v"(c));
    return d;
}
// v_pk_fma_f32 with src0 broadcast from HI half
__device__ __forceinline__ float2 pk_fma_bhi(float2 a, float2 b, float2 c){
    float2 d;
    asm("v_pk_fma_f32 %0, %1, %2, %3 op_sel:[1,0,0] op_sel_hi:[1,1,1]" : "=v"(d) : "v"(a), "v"(b), "v"(c));
    return d;
}

// pack two f32 -> two bf16 (RNE) in one dword: lo16 = bf16(a), hi16 = bf16(b)
__device__ __forceinline__ uint32_t cvt_pk_bf16(float a, float b){
    uint32_t r;
    asm("v_cvt_pk_bf16_f32 %0, %1, %2" : "=v"(r) : "v"(a), "v"(b));
    return r;
}

// 64-lane sum via DPP; result valid in lane 63.
__device__ __forceinline__ float waveRedDpp(float x){
    x += __int_as_float(__builtin_amdgcn_update_dpp(0, __float_as_int(x), 0x111, 0xf, 0xf, false)); // row_shr:1
    x += __int_as_float(__builtin_amdgcn_update_dpp(0, __float_as_int(x), 0x112, 0xf, 0xf, false)); // row_shr:2
    x += __int_as_float(__builtin_amdgcn_update_dpp(0, __float_as_int(x), 0x114, 0xf, 0xf, false)); // row_shr:4
    x += __int_as_float(__builtin_amdgcn_update_dpp(0, __float_as_int(x), 0x118, 0xf, 0xf, false)); // row_shr:8
    x += __int_as_float(__builtin_amdgcn_update_dpp(0, __float_as_int(x), 0x142, 0xa, 0xf, false)); // row_bcast:15
    x += __int_as_float(__builtin_amdgcn_update_dpp(0, __float_as_int(x), 0x143, 0xc, 0xf, false)); // row_bcast:31
    return x;
}

// ---------------- K0: prepack X rows ----------------
// X'[row] = [n0 n1 n2 n3 | n4 n5 n6 evByteOffsetBits]
__global__ __launch_bounds__(256) void k0_prep(const float* __restrict__ X, float* __restrict__ Xp)
{
    const int r = blockIdx.x*256 + threadIdx.x;     // r < BN*SN
    const float4* src = (const float4*)(X + (size_t)r*8);
    const float4 a = src[0], b4 = src[1];
    float4* dst = (float4*)(Xp + (size_t)r*8);
    dst[0] = make_float4(a.y, a.z, a.w, b4.x);
    dst[1] = make_float4(b4.y, b4.z, b4.w, __int_as_float((int)a.x * (HDIM*8)));
}

// ---------------- K1: fold emb/bias/num path into INTERLEAVED, PRE-SCALED tables ----------------
// T[(dir,v,j)] = float2(CZ*z-col j, CF*f-col j); U likewise (so exp2 applies directly).
__global__ __launch_bounds__(512) void k1_tables(
    const float* __restrict__ emb, const float* __restrict__ num_W, const float* __restrict__ num_b,
    const float* __restrict__ Wf, const float* __restrict__ bf,
    const float* __restrict__ Wb, const float* __restrict__ bb,
    float* __restrict__ T, float* __restrict__ U)
{
    const int blk = blockIdx.x;
    const int c = threadIdx.x;
    const int j = c & (HDIM-1);
    const int g = c >> 8;               // 0 -> z gate, 1 -> f gate
    const int col = g*HDIM + j;
    const float gs = g ? CF : CZ;
    if (blk < 2*VOCABN) {
        const int dir = blk & 1, v = blk >> 1;
        const float* W    = dir ? Wb : Wf;
        const float* bias = dir ? bb : bf;
        float acc = bias[col];
        const float* e = emb + (size_t)v*EMBN;
        #pragma unroll 8
        for (int k=0;k<EMBN;++k) acc = fmaf(e[k], W[(size_t)k*768 + col], acc);
        #pragma unroll
        for (int m=0;m<4;++m)    acc = fmaf(num_b[m], W[(size_t)(EMBN+m)*768 + col], acc);
        T[(((size_t)dir*VOCABN + v)*HDIM + j)*2 + g] = acc * gs;
    } else {
        const int dir = blk - 2*VOCABN;
        const float* W = dir ? Wb : Wf;
        #pragma unroll
        for (int i=0;i<NUMIN;++i){
            float acc = 0.f;
            #pragma unroll
            for (int m=0;m<4;++m) acc = fmaf(num_W[i*4+m], W[(size_t)(EMBN+m)*768 + col], acc);
            U[(((size_t)dir*8 + i)*HDIM + j)*2 + g] = acc * gs;
        }
    }
}

// ---------------- K2: segmented fo-pool scan, 2 channels/thread (j, j+128), LDS X-feed ----------------
// MODE 0: per-segment affine coefficients a=prod(f), c=scan from 0.
// MODE 1: scan from hstart, score partials via DPP reduce, AND store h as packed bf16.
// MODE 2: scan from hstart, ctx += w[s]*h (recompute fallback, no h storage).
// MODE 3: scan from hstart, score partials only (fallback when h2 doesn't fit ws).
// Block=(b,dir,seg), 128 threads; thread j owns channels j and j+128 (R11 mapping).
// X rows staged in LDS once (2KB, conflict-free) -> in-loop feed is broadcast ds_read
// (IN-ORDER lgkmcnt, compiler pipelines precisely; no SMEM drain-all stall).
// T rows: depth-3 register ring via vmcnt, byte offsets from LDS evb[].
template<int MODE>
__global__ __launch_bounds__(128) void k2_scan(
    const float* __restrict__ Xp, const float* __restrict__ T, const float* __restrict__ U,
    const float* __restrict__ Mu, const float* __restrict__ w,
    const float* __restrict__ hstart,
    float* __restrict__ aArr, float* __restrict__ cArr,
    float* __restrict__ swp, float* __restrict__ ctxp, uint32_t* __restrict__ h2)
{
    const int bid = blockIdx.x;
    const int seg = bid & (SEG-1);
    const int dir = (bid >> 5) & 1;
    const int b   = bid >> 6;
    const int j   = threadIdx.x;            // 0..127
    const int blk = (b*2+dir)*SEG + seg;
    const size_t segIdx = (size_t)blk*HDIM + j;   // channel j; +128 for hi channel

    const float2* Td2 = (const float2*)T + (size_t)dir*VOCABN*HDIM;
    const float2* Ud2 = (const float2*)U + (size_t)dir*8*HDIM;
    float2 uLo0=Ud2[0*HDIM+j],     uLo1=Ud2[1*HDIM+j],     uLo2=Ud2[2*HDIM+j],
           uLo3=Ud2[3*HDIM+j],     uLo4=Ud2[4*HDIM+j],     uLo5=Ud2[5*HDIM+j],
           uLo6=Ud2[6*HDIM+j];
    float2 uHi0=Ud2[0*HDIM+j+128], uHi1=Ud2[1*HDIM+j+128], uHi2=Ud2[2*HDIM+j+128],
           uHi3=Ud2[3*HDIM+j+128], uHi4=Ud2[4*HDIM+j+128], uHi5=Ud2[5*HDIM+j+128],
           uHi6=Ud2[6*HDIM+j+128];
    const float muLo = (MODE==1 || MODE==3) ? Mu[dir*HDIM + j]       : 0.f;
    const float muHi = (MODE==1 || MODE==3) ? Mu[dir*HDIM + j + 128] : 0.f;

    const int sBeg = seg*SEGLEN;
    const float* wb = w + (size_t)b*SN + sBeg;     // MODE2 fallback weights
    const char* Tb = (const char*)Td2;
    const int j8 = j*8;

    __shared__ float4 xlds[SEGLEN][2];   // [n0 n1 n2 n3][n4 n5 n6 evbits]
    __shared__ int    evb[SEGLEN];       // T-row byte offsets (ev*2048)

    {   // staging: thread t -> row t/2, half t&1 (contiguous 16B stores, conflict-free)
        const int r = j >> 1, half = j & 1;
        const int gp = b*SN + (dir ? (SN-1-(sBeg+r)) : (sBeg+r));   // FIX: batch offset!
        const float4 v4 = *(const float4*)(Xp + (size_t)gp*8 + half*4);
        xlds[r][half] = v4;
        if (half) evb[r] = __float_as_int(v4.w);
    }
    __syncthreads();

    float hLo = (MODE==0) ? 0.f : hstart[segIdx];
    float hHi = (MODE==0) ? 0.f : hstart[segIdx + 128];
    float aaccLo = 1.f, aaccHi = 1.f;
    float ctxLo = 0.f, ctxHi = 0.f;
    float hpLo = 0.f, hpHi = 0.f;
    float* swpp = swp + (size_t)(b*4 + dir*2 + (j>>6))*SN + sBeg;
    uint32_t* h2p = h2 + (size_t)blk*(SEGLEN/2)*HDIM + j;

    // prologue: X ring depth 2, T ring depth 3, ev 1 ahead of T issue
    float4 xa0 = xlds[0][0], xb0 = xlds[0][1];
    float4 xa1 = xlds[1][0], xb1 = xlds[1][1];
    int e3 = evb[3];
    const char* tq0 = Tb + (uint32_t)evb[0];
    const char* tq1 = Tb + (uint32_t)evb[1];
    const char* tq2 = Tb + (uint32_t)evb[2];
    float2 tLo0 = *(const float2*)(tq0 + j8), tHi0 = *(const float2*)(tq0 + j8 + 1024);
    float2 tLo1 = *(const float2*)(tq1 + j8), tHi1 = *(const float2*)(tq1 + j8 + 1024);
    float2 tLo2 = *(const float2*)(tq2 + j8), tHi2 = *(const float2*)(tq2 + j8 + 1024);

    #pragma unroll 4
    for (int si=0; si<SEGLEN; ++si){
        // prefetch: T row si+3 (ev read 1 iter ago), X row si+2, ev row si+4
        const char* tq3 = Tb + (uint32_t)e3;
        const float2 tLo3 = *(const float2*)(tq3 + j8);
        const float2 tHi3 = *(const float2*)(tq3 + j8 + 1024);
        const int i2 = (si+2 < SEGLEN) ? si+2 : SEGLEN-1;
        const float4 xan = xlds[i2][0];
        const float4 xbn = xlds[i2][1];
        const int i4 = (si+4 < SEGLEN) ? si+4 : SEGLEN-1;
        const int en = evb[i4];

        const float2 xp01 = make_float2(xa0.x, xa0.y);
        const float2 xp23 = make_float2(xa0.z, xa0.w);
        const float2 xp45 = make_float2(xb0.x, xb0.y);
        const float2 xp6e = make_float2(xb0.z, xb0.w);
        float2 zfLo = tLo0, zfHi = tHi0;
        zfLo = pk_fma_blo(xp01, uLo0, zfLo);  zfHi = pk_fma_blo(xp01, uHi0, zfHi);  // n0
        zfLo = pk_fma_bhi(xp01, uLo1, zfLo);  zfHi = pk_fma_bhi(xp01, uHi1, zfHi);  // n1
        zfLo = pk_fma_blo(xp23, uLo2, zfLo);  zfHi = pk_fma_blo(xp23, uHi2, zfHi);  // n2
        zfLo = pk_fma_bhi(xp23, uLo3, zfLo);  zfHi = pk_fma_bhi(xp23, uHi3, zfHi);  // n3
        zfLo = pk_fma_blo(xp45, uLo4, zfLo);  zfHi = pk_fma_blo(xp45, uHi4, zfHi);  // n4
        zfLo = pk_fma_bhi(xp45, uLo5, zfLo);  zfHi = pk_fma_bhi(xp45, uHi5, zfHi);  // n5
        zfLo = pk_fma_blo(xp6e, uLo6, zfLo);  zfHi = pk_fma_blo(xp6e, uHi6, zfHi);  // n6

        // gates, one reciprocal per channel (zf pre-scaled by CZ/CF)
        const float e2zL = fast_exp2(zfLo.x), efL = fast_exp2(zfLo.y);
        const float e2zH = fast_exp2(zfHi.x), efH = fast_exp2(zfHi.y);
        const float a2L = 1.f + e2zL, a1L = 1.f + efL;
        const float a2H = 1.f + e2zH, a1H = 1.f + efH;
        const float rL = rcpf(a1L * a2L);
        const float rH = rcpf(a1H * a2H);
        hLo = fmaf(efL * hLo, a2L, e2zL - 1.f) * rL;
        hHi = fmaf(efH * hHi, a2H, e2zH - 1.f) * rH;

        if (MODE==0){
            aaccLo *= efL * a2L * rL;            // f = ef/(1+ef)
            aaccHi *= efH * a2H * rH;
        } else if (MODE==1 || MODE==3){
            float pr = waveRedDpp(fmaf(hHi, muHi, hLo * muLo));
            if ((j & 63) == 63) swpp[si] = pr;
            if (MODE==1){
                if (si & 1){
                    h2p[0]   = cvt_pk_bf16(hpLo, hLo);
                    h2p[128] = cvt_pk_bf16(hpHi, hHi);
                    h2p += HDIM;
                } else { hpLo = hLo; hpHi = hHi; }
            }
        } else {
            const float ws_ = wb[si];
            ctxLo = fmaf(ws_, hLo, ctxLo);
            ctxHi = fmaf(ws_, hHi, ctxHi);
        }
        // rotate rings
        xa0=xa1; xb0=xb1; xa1=xan; xb1=xbn;
        tLo0=tLo1; tHi0=tHi1; tLo1=tLo2; tHi1=tHi2; tLo2=tLo3; tHi2=tHi3;
        e3 = en;
    }
    if (MODE==0){
        aArr[segIdx] = aaccLo; aArr[segIdx+128] = aaccHi;
        cArr[segIdx] = hLo;    cArr[segIdx+128] = hHi;
    }
    if (MODE==2){ ctxp[segIdx] = ctxLo; ctxp[segIdx+128] = ctxHi; }
}

// ---------------- compose: hstart[seg] = h; h = a*h + c ----------------
__global__ __launch_bounds__(256) void k_compose(const float* __restrict__ aArr, const float* __restrict__ cArr,
                                                 float* __restrict__ hstart)
{
    const int bd = blockIdx.x;   // b*2 + dir
    const int j  = threadIdx.x;
    float h = 0.f;
    #pragma unroll
    for (int seg=0; seg<SEG; ++seg){
        const size_t idx = ((size_t)bd*SEG + seg)*HDIM + j;
        hstart[idx] = h;
        h = fmaf(aArr[idx], h, cArr[idx]);
    }
}

// ---------------- K3: softmax over S per batch (4 partial rows per b) ----------------
__global__ __launch_bounds__(256) void k3_softmax(const float* __restrict__ swp, float* __restrict__ w)
{
    __shared__ float sc[SN];
    __shared__ float red[4];
    const int b = blockIdx.x, t = threadIdx.x;
    for (int s=t; s<SN; s+=256){
        float acc = 0.f;
        #pragma unroll
        for (int r=0;r<4;++r) acc += swp[((size_t)b*4 + r)*SN + s];
        sc[s] = acc;
    }
    __syncthreads();
    float m = -3.4e38f;
    for (int s=t; s<SN; s+=256) m = fmaxf(m, sc[s]);
    #pragma unroll
    for (int o=32;o;o>>=1) m = fmaxf(m, __shfl_xor(m,o,64));
    if ((t&63)==0) red[t>>6] = m;
    __syncthreads();
    m = fmaxf(fmaxf(red[0],red[1]), fmaxf(red[2],red[3]));
    float zs = 0.f;
    for (int s=t; s<SN; s+=256){
        float e = __expf(sc[s]-m);
        sc[s] = e;
        zs += e;
    }
    #pragma unroll
    for (int o=32;o;o>>=1) zs += __shfl_xor(zs,o,64);
    __syncthreads();
    if ((t&63)==0) red[t>>6] = zs;
    __syncthreads();
    zs = red[0]+red[1]+red[2]+red[3];
    float invz = rcpf(zs);
    for (int s=t; s<SN; s+=256) w[(size_t)b*SN + s] = sc[s]*invz;
}

// ---------------- K4: ctx from stored bf16 h (memory-bound replay) ----------------
__global__ __launch_bounds__(256) void k4_ctx(const uint32_t* __restrict__ h2, const float* __restrict__ w,
                                              float* __restrict__ ctxp)
{
    const int bid = blockIdx.x;
    const int seg = bid & (SEG-1);
    const int dir = (bid >> 5) & 1;
    const int b   = bid >> 6;
    const int blk = (b*2+dir)*SEG + seg;
    const int j   = threadIdx.x;
    const float* wb = w + (size_t)b*SN + seg*SEGLEN;
    const uint32_t* hp = h2 + (size_t)blk*(SEGLEN/2)*HDIM + j;
    float acc = 0.f;
    #pragma unroll 8
    for (int si2=0; si2<SEGLEN/2; ++si2){
        const uint32_t pk = hp[(size_t)si2*HDIM];
        const float hlo = __int_as_float(pk << 16);
        const float hhi = __int_as_float(pk & 0xffff0000u);
        acc = fmaf(wb[2*si2  ], hlo, acc);
        acc = fmaf(wb[2*si2+1], hhi, acc);
    }
    ctxp[(size_t)blk*HDIM + j] = acc;
}

// ---------------- K5: out[b] = (sum_seg ctxp) . out_W + out_b ----------------
__global__ __launch_bounds__(512) void k5_out(const float* __restrict__ ctxp, const float* __restrict__ out_W,
                                              const float* __restrict__ out_b, float* __restrict__ out)
{
    __shared__ float red[8];
    const int b = blockIdx.x, c = threadIdx.x;
    const int dir = c >> 8, j = c & (HDIM-1);
    float acc = 0.f;
    #pragma unroll
    for (int seg=0; seg<SEG; ++seg)
        acc += ctxp[((size_t)(b*2+dir)*SEG + seg)*HDIM + j];
    float p = acc * out_W[c];
    #pragma unroll
    for (int o=32;o;o>>=1) p += __shfl_xor(p,o,64);
    if ((c&63)==0) red[c>>6] = p;
    __syncthreads();
    if (c==0){
        float t = 0.f;
        #pragma unroll
        for (int r=0;r<8;++r) t += red[r];
        out[b] = t + out_b[0];
    }
}

extern "C" void kernel_launch(void* const* d_in, const int* in_sizes, int n_in,
                              void* d_out, int out_size, void* d_ws, size_t ws_size,
                              hipStream_t stream)
{
    const float* X     = (const float*)d_in[0];
    const float* emb   = (const float*)d_in[1];
    const float* num_W = (const float*)d_in[2];
    const float* num_b = (const float*)d_in[3];
    const float* Wf    = (const float*)d_in[4];
    const float* bf    = (const float*)d_in[5];
    const float* Wb    = (const float*)d_in[6];
    const float* bb    = (const float*)d_in[7];
    const float* Mu    = (const float*)d_in[8];
    const float* out_W = (const float*)d_in[9];
    const float* out_b = (const float*)d_in[10];
    float* out = (float*)d_out;

    float* ws = (float*)d_ws;
    size_t off = 0;
    float* swp   = ws + off; off += (size_t)BN*4*SN;           // 2 MB (4 partial rows per b)
    float* w     = ws + off; off += (size_t)BN*SN;             // 0.5 MB
    float* T     = ws + off; off += (size_t)2*VOCABN*TWOH;     // interleaved, pre-scaled
    float* U     = ws + off; off += (size_t)2*8*TWOH;          // interleaved, pre-scaled
    float* aArr  = ws + off; off += (size_t)BN*2*SEG*HDIM;     // 4 MB
    float* cArr  = ws + off; off += (size_t)BN*2*SEG*HDIM;     // 4 MB
    float* hstart= ws + off; off += (size_t)BN*2*SEG*HDIM;     // 4 MB
    float* ctxp  = ws + off; off += (size_t)BN*2*SEG*HDIM;     // 4 MB
    float* Xp    = ws + off; off += (size_t)BN*SN*8;           // 4 MB prepacked X
    uint32_t* h2 = (uint32_t*)(ws + off);
    off += (size_t)BN*2*SEG*(SEGLEN/2)*HDIM;                   // 128 MB packed bf16 h
    const bool useStore = ((size_t)off * sizeof(float)) <= ws_size;

    hipLaunchKernelGGL(k0_prep,     dim3(BN*SN/256),   dim3(256), 0, stream, X, Xp);
    hipLaunchKernelGGL(k1_tables,   dim3(2*VOCABN+2),  dim3(512), 0, stream,
                       emb, num_W, num_b, Wf, bf, Wb, bb, T, U);
    hipLaunchKernelGGL(k2_scan<0>,  dim3(BN*2*SEG),    dim3(128), 0, stream,
                       Xp, T, U, Mu, w, hstart, aArr, cArr, swp, ctxp, h2);
    hipLaunchKernelGGL(k_compose,   dim3(BN*2),        dim3(256), 0, stream,
                       aArr, cArr, hstart);
    if (useStore) {
        hipLaunchKernelGGL(k2_scan<1>, dim3(BN*2*SEG), dim3(128), 0, stream,
                           Xp, T, U, Mu, w, hstart, aArr, cArr, swp, ctxp, h2);
        hipLaunchKernelGGL(k3_softmax, dim3(BN),       dim3(256), 0, stream, swp, w);
        hipLaunchKernelGGL(k4_ctx,     dim3(BN*2*SEG), dim3(256), 0, stream, h2, w, ctxp);
    } else {
        hipLaunchKernelGGL(k2_scan<3>, dim3(BN*2*SEG), dim3(128), 0, stream,
                           Xp, T, U, Mu, w, hstart, aArr, cArr, swp, ctxp, h2);
        hipLaunchKernelGGL(k3_softmax, dim3(BN),       dim3(256), 0, stream, swp, w);
        hipLaunchKernelGGL(k2_scan<2>, dim3(BN*2*SEG), dim3(128), 0, stream,
                           Xp, T, U, Mu, w, hstart, aArr, cArr, swp, ctxp, h2);
    }
    hipLaunchKernelGGL(k5_out,      dim3(BN),          dim3(512), 0, stream,
                       ctxp, out_W, out_b, out);
}

// Round 15
// 151.254 us; speedup vs baseline: 1.4237x; 1.0553x over previous
//
#include <hip/hip_runtime.h>
#include <stdint.h>

#define VOCABN 64
#define EMBN   128
#define HDIM   256
#define NUMIN  7
#define BN     64
#define SN     2048
#define TWOH   512
#define SEG    32
#define SEGLEN 64

#define CZ 2.8853900818f   // 2*log2(e)
#define CF 1.4426950409f   // log2(e)

__device__ __forceinline__ float rcpf(float x){ return __builtin_amdgcn_rcpf(x); }

__device__ __forceinline__ float fast_exp2(float x){
#if __has_builtin(__builtin_amdgcn_exp2f)
    return __builtin_amdgcn_exp2f(x);
#else
    return exp2f(x);
#endif
}

// v_pk_fma_f32 with src0 broadcast from LO half (both result lanes use src0.lo)
__device__ __forceinline__ float2 pk_fma_blo(float2 a, float2 b, float2 c){
    float2 d;
    asm("v_pk_fma_f32 %0, %1, %2, %3 op_sel_hi:[0,1,1]" : "=v"(d) : "v"(a), "v"(b), "v"(c));
    return d;
}
// v_pk_fma_f32 with src0 broadcast from HI half
__device__ __forceinline__ float2 pk_fma_bhi(float2 a, float2 b, float2 c){
    float2 d;
    asm("v_pk_fma_f32 %0, %1, %2, %3 op_sel:[1,0,0] op_sel_hi:[1,1,1]" : "=v"(d) : "v"(a), "v"(b), "v"(c));
    return d;
}

// pack two f32 -> two bf16 (RNE) in one dword: lo16 = bf16(a), hi16 = bf16(b)
__device__ __forceinline__ uint32_t cvt_pk_bf16(float a, float b){
    uint32_t r;
    asm("v_cvt_pk_bf16_f32 %0, %1, %2" : "=v"(r) : "v"(a), "v"(b));
    return r;
}

// 64-lane sum via DPP; result valid in lane 63.
__device__ __forceinline__ float waveRedDpp(float x){
    x += __int_as_float(__builtin_amdgcn_update_dpp(0, __float_as_int(x), 0x111, 0xf, 0xf, false)); // row_shr:1
    x += __int_as_float(__builtin_amdgcn_update_dpp(0, __float_as_int(x), 0x112, 0xf, 0xf, false)); // row_shr:2
    x += __int_as_float(__builtin_amdgcn_update_dpp(0, __float_as_int(x), 0x114, 0xf, 0xf, false)); // row_shr:4
    x += __int_as_float(__builtin_amdgcn_update_dpp(0, __float_as_int(x), 0x118, 0xf, 0xf, false)); // row_shr:8
    x += __int_as_float(__builtin_amdgcn_update_dpp(0, __float_as_int(x), 0x142, 0xa, 0xf, false)); // row_bcast:15
    x += __int_as_float(__builtin_amdgcn_update_dpp(0, __float_as_int(x), 0x143, 0xc, 0xf, false)); // row_bcast:31
    return x;
}

// ---------------- K0: prepack X rows ----------------
// X'[row] = [n0 n1 n2 n3 | n4 n5 n6 evByteOffsetBits]
__global__ __launch_bounds__(256) void k0_prep(const float* __restrict__ X, float* __restrict__ Xp)
{
    const int r = blockIdx.x*256 + threadIdx.x;     // r < BN*SN
    const float4* src = (const float4*)(X + (size_t)r*8);
    const float4 a = src[0], b4 = src[1];
    float4* dst = (float4*)(Xp + (size_t)r*8);
    dst[0] = make_float4(a.y, a.z, a.w, b4.x);
    dst[1] = make_float4(b4.y, b4.z, b4.w, __int_as_float((int)a.x * (HDIM*8)));
}

// ---------------- K1: fold emb/bias/num path into CHANNEL-PAIRED, PRE-SCALED tables ----------------
// T'[(dir,v,j)] = float4(CZ*z_j, CF*f_j, CZ*z_{j+128}, CF*f_{j+128})  (j<128; row = 2048B as before)
// U'[(dir,i,j)] likewise.
__global__ __launch_bounds__(512) void k1_tables(
    const float* __restrict__ emb, const float* __restrict__ num_W, const float* __restrict__ num_b,
    const float* __restrict__ Wf, const float* __restrict__ bf,
    const float* __restrict__ Wb, const float* __restrict__ bb,
    float* __restrict__ T, float* __restrict__ U)
{
    const int blk = blockIdx.x;
    const int c = threadIdx.x;
    const int jj = c & (HDIM-1);        // channel 0..255
    const int g = c >> 8;               // 0 -> z gate, 1 -> f gate
    const int col = g*HDIM + jj;
    const float gs = g ? CF : CZ;
    const int comp = ((jj >> 7) << 1) + g;      // float4 component
    const int rowj = jj & 127;                  // float4 index within row
    if (blk < 2*VOCABN) {
        const int dir = blk & 1, v = blk >> 1;
        const float* W    = dir ? Wb : Wf;
        const float* bias = dir ? bb : bf;
        float acc = bias[col];
        const float* e = emb + (size_t)v*EMBN;
        #pragma unroll 8
        for (int k=0;k<EMBN;++k) acc = fmaf(e[k], W[(size_t)k*768 + col], acc);
        #pragma unroll
        for (int m=0;m<4;++m)    acc = fmaf(num_b[m], W[(size_t)(EMBN+m)*768 + col], acc);
        T[(((size_t)dir*VOCABN + v)*128 + rowj)*4 + comp] = acc * gs;
    } else {
        const int dir = blk - 2*VOCABN;
        const float* W = dir ? Wb : Wf;
        #pragma unroll
        for (int i=0;i<NUMIN;++i){
            float acc = 0.f;
            #pragma unroll
            for (int m=0;m<4;++m) acc = fmaf(num_W[i*4+m], W[(size_t)(EMBN+m)*768 + col], acc);
            U[(((size_t)dir*8 + i)*128 + rowj)*4 + comp] = acc * gs;
        }
    }
}

// ---------------- K2: segmented fo-pool scan, 2 channels/thread (j, j+128), LDS X-feed ----------------
// MODE 0: per-segment affine coefficients a=prod(f), c=scan from 0.
// MODE 1: scan from hstart, score partials via DPP reduce, AND store h as packed bf16.
// MODE 2: scan from hstart, ctx += w[s]*h (recompute fallback, no h storage).
// MODE 3: scan from hstart, score partials only (fallback when h2 doesn't fit ws).
// Block=(b,dir,seg), 128 threads; thread j owns channels j and j+128.
// X rows staged in LDS once (2KB, conflict-free); T rows: ONE dwordx4/step
// (channel-paired layout), depth-3 register ring, 32-bit voffset addressing.
template<int MODE>
__global__ __launch_bounds__(128) void k2_scan(
    const float* __restrict__ Xp, const float* __restrict__ T, const float* __restrict__ U,
    const float* __restrict__ Mu, const float* __restrict__ w,
    const float* __restrict__ hstart,
    float* __restrict__ aArr, float* __restrict__ cArr,
    float* __restrict__ swp, float* __restrict__ ctxp, uint32_t* __restrict__ h2)
{
    const int bid = blockIdx.x;
    const int seg = bid & (SEG-1);
    const int dir = (bid >> 5) & 1;
    const int b   = bid >> 6;
    const int j   = threadIdx.x;            // 0..127
    const int blk = (b*2+dir)*SEG + seg;
    const size_t segIdx = (size_t)blk*HDIM + j;   // channel j; +128 for hi channel

    const char* Tb = (const char*)T + (size_t)dir*VOCABN*2048;  // row = 2048B
    const float4* Ud4 = (const float4*)U + (size_t)dir*8*128;
    const float4 u0q = Ud4[0*128+j], u1q = Ud4[1*128+j], u2q = Ud4[2*128+j],
                 u3q = Ud4[3*128+j], u4q = Ud4[4*128+j], u5q = Ud4[5*128+j],
                 u6q = Ud4[6*128+j];
    const float2 uLo0 = make_float2(u0q.x,u0q.y), uHi0 = make_float2(u0q.z,u0q.w);
    const float2 uLo1 = make_float2(u1q.x,u1q.y), uHi1 = make_float2(u1q.z,u1q.w);
    const float2 uLo2 = make_float2(u2q.x,u2q.y), uHi2 = make_float2(u2q.z,u2q.w);
    const float2 uLo3 = make_float2(u3q.x,u3q.y), uHi3 = make_float2(u3q.z,u3q.w);
    const float2 uLo4 = make_float2(u4q.x,u4q.y), uHi4 = make_float2(u4q.z,u4q.w);
    const float2 uLo5 = make_float2(u5q.x,u5q.y), uHi5 = make_float2(u5q.z,u5q.w);
    const float2 uLo6 = make_float2(u6q.x,u6q.y), uHi6 = make_float2(u6q.z,u6q.w);
    const float muLo = (MODE==1 || MODE==3) ? Mu[dir*HDIM + j]       : 0.f;
    const float muHi = (MODE==1 || MODE==3) ? Mu[dir*HDIM + j + 128] : 0.f;

    const int sBeg = seg*SEGLEN;
    const float* wb = w + (size_t)b*SN + sBeg;     // MODE2 fallback weights
    const int j16 = j*16;

    __shared__ float4 xlds[SEGLEN][2];   // [n0 n1 n2 n3][n4 n5 n6 evbits]
    __shared__ int    evb[SEGLEN];       // T-row byte offsets (ev*2048)

    {   // staging: thread t -> row t/2, half t&1 (contiguous 16B stores, conflict-free)
        const int r = j >> 1, half = j & 1;
        const int gp = b*SN + (dir ? (SN-1-(sBeg+r)) : (sBeg+r));
        const float4 v4 = *(const float4*)(Xp + (size_t)gp*8 + half*4);
        xlds[r][half] = v4;
        if (half) evb[r] = __float_as_int(v4.w);
    }
    __syncthreads();

    float hLo = (MODE==0) ? 0.f : hstart[segIdx];
    float hHi = (MODE==0) ? 0.f : hstart[segIdx + 128];
    float aaccLo = 1.f, aaccHi = 1.f;
    float ctxLo = 0.f, ctxHi = 0.f;
    float hpLo = 0.f, hpHi = 0.f;
    float* swpp = swp + (size_t)(b*4 + dir*2 + (j>>6))*SN + sBeg;
    uint32_t* h2p = h2 + (size_t)blk*(SEGLEN/2)*HDIM + j;

    // prologue: X ring depth 2, T ring depth 3 (one dwordx4 each), ev 1 ahead of T issue
    float4 xa0 = xlds[0][0], xb0 = xlds[0][1];
    float4 xa1 = xlds[1][0], xb1 = xlds[1][1];
    int e3 = evb[3];
    float4 t0 = *(const float4*)(Tb + (uint32_t)(evb[0] + j16));
    float4 t1 = *(const float4*)(Tb + (uint32_t)(evb[1] + j16));
    float4 t2 = *(const float4*)(Tb + (uint32_t)(evb[2] + j16));

    #pragma unroll 8
    for (int si=0; si<SEGLEN; ++si){
        // prefetch: T row si+3 (ev read 1 iter ago), X row si+2, ev row si+4
        const float4 t3 = *(const float4*)(Tb + (uint32_t)(e3 + j16));
        const int i2 = (si+2 < SEGLEN) ? si+2 : SEGLEN-1;
        const float4 xan = xlds[i2][0];
        const float4 xbn = xlds[i2][1];
        const int i4 = (si+4 < SEGLEN) ? si+4 : SEGLEN-1;
        const int en = evb[i4];

        const float2 xp01 = make_float2(xa0.x, xa0.y);
        const float2 xp23 = make_float2(xa0.z, xa0.w);
        const float2 xp45 = make_float2(xb0.x, xb0.y);
        const float2 xp6e = make_float2(xb0.z, xb0.w);
        float2 zfLo = make_float2(t0.x, t0.y);
        float2 zfHi = make_float2(t0.z, t0.w);
        zfLo = pk_fma_blo(xp01, uLo0, zfLo);  zfHi = pk_fma_blo(xp01, uHi0, zfHi);  // n0
        zfLo = pk_fma_bhi(xp01, uLo1, zfLo);  zfHi = pk_fma_bhi(xp01, uHi1, zfHi);  // n1
        zfLo = pk_fma_blo(xp23, uLo2, zfLo);  zfHi = pk_fma_blo(xp23, uHi2, zfHi);  // n2
        zfLo = pk_fma_bhi(xp23, uLo3, zfLo);  zfHi = pk_fma_bhi(xp23, uHi3, zfHi);  // n3
        zfLo = pk_fma_blo(xp45, uLo4, zfLo);  zfHi = pk_fma_blo(xp45, uHi4, zfHi);  // n4
        zfLo = pk_fma_bhi(xp45, uLo5, zfLo);  zfHi = pk_fma_bhi(xp45, uHi5, zfHi);  // n5
        zfLo = pk_fma_blo(xp6e, uLo6, zfLo);  zfHi = pk_fma_blo(xp6e, uHi6, zfHi);  // n6

        // gates, one reciprocal per channel (zf pre-scaled by CZ/CF)
        const float e2zL = fast_exp2(zfLo.x), efL = fast_exp2(zfLo.y);
        const float e2zH = fast_exp2(zfHi.x), efH = fast_exp2(zfHi.y);
        const float a2L = 1.f + e2zL, a1L = 1.f + efL;
        const float a2H = 1.f + e2zH, a1H = 1.f + efH;
        const float rL = rcpf(a1L * a2L);
        const float rH = rcpf(a1H * a2H);
        hLo = fmaf(efL * hLo, a2L, e2zL - 1.f) * rL;
        hHi = fmaf(efH * hHi, a2H, e2zH - 1.f) * rH;

        if (MODE==0){
            aaccLo *= efL * a2L * rL;            // f = ef/(1+ef)
            aaccHi *= efH * a2H * rH;
        } else if (MODE==1 || MODE==3){
            float pr = waveRedDpp(fmaf(hHi, muHi, hLo * muLo));
            if ((j & 63) == 63) swpp[si] = pr;
            if (MODE==1){
                if (si & 1){
                    h2p[0]   = cvt_pk_bf16(hpLo, hLo);
                    h2p[128] = cvt_pk_bf16(hpHi, hHi);
                    h2p += HDIM;
                } else { hpLo = hLo; hpHi = hHi; }
            }
        } else {
            const float ws_ = wb[si];
            ctxLo = fmaf(ws_, hLo, ctxLo);
            ctxHi = fmaf(ws_, hHi, ctxHi);
        }
        // rotate rings
        xa0=xa1; xb0=xb1; xa1=xan; xb1=xbn;
        t0=t1; t1=t2; t2=t3; e3=en;
    }
    if (MODE==0){
        aArr[segIdx] = aaccLo; aArr[segIdx+128] = aaccHi;
        cArr[segIdx] = hLo;    cArr[segIdx+128] = hHi;
    }
    if (MODE==2){ ctxp[segIdx] = ctxLo; ctxp[segIdx+128] = ctxHi; }
}

// ---------------- compose: hstart[seg] = h; h = a*h + c ----------------
__global__ __launch_bounds__(256) void k_compose(const float* __restrict__ aArr, const float* __restrict__ cArr,
                                                 float* __restrict__ hstart)
{
    const int bd = blockIdx.x;   // b*2 + dir
    const int j  = threadIdx.x;
    float h = 0.f;
    #pragma unroll
    for (int seg=0; seg<SEG; ++seg){
        const size_t idx = ((size_t)bd*SEG + seg)*HDIM + j;
        hstart[idx] = h;
        h = fmaf(aArr[idx], h, cArr[idx]);
    }
}

// ---------------- K3: softmax over S per batch (4 partial rows per b) ----------------
__global__ __launch_bounds__(256) void k3_softmax(const float* __restrict__ swp, float* __restrict__ w)
{
    __shared__ float sc[SN];
    __shared__ float red[4];
    const int b = blockIdx.x, t = threadIdx.x;
    for (int s=t; s<SN; s+=256){
        float acc = 0.f;
        #pragma unroll
        for (int r=0;r<4;++r) acc += swp[((size_t)b*4 + r)*SN + s];
        sc[s] = acc;
    }
    __syncthreads();
    float m = -3.4e38f;
    for (int s=t; s<SN; s+=256) m = fmaxf(m, sc[s]);
    #pragma unroll
    for (int o=32;o;o>>=1) m = fmaxf(m, __shfl_xor(m,o,64));
    if ((t&63)==0) red[t>>6] = m;
    __syncthreads();
    m = fmaxf(fmaxf(red[0],red[1]), fmaxf(red[2],red[3]));
    float zs = 0.f;
    for (int s=t; s<SN; s+=256){
        float e = __expf(sc[s]-m);
        sc[s] = e;
        zs += e;
    }
    #pragma unroll
    for (int o=32;o;o>>=1) zs += __shfl_xor(zs,o,64);
    __syncthreads();
    if ((t&63)==0) red[t>>6] = zs;
    __syncthreads();
    zs = red[0]+red[1]+red[2]+red[3];
    float invz = rcpf(zs);
    for (int s=t; s<SN; s+=256) w[(size_t)b*SN + s] = sc[s]*invz;
}

// ---------------- K4: ctx from stored bf16 h (memory-bound replay) ----------------
__global__ __launch_bounds__(256) void k4_ctx(const uint32_t* __restrict__ h2, const float* __restrict__ w,
                                              float* __restrict__ ctxp)
{
    const int bid = blockIdx.x;
    const int seg = bid & (SEG-1);
    const int dir = (bid >> 5) & 1;
    const int b   = bid >> 6;
    const int blk = (b*2+dir)*SEG + seg;
    const int j   = threadIdx.x;
    const float* wb = w + (size_t)b*SN + seg*SEGLEN;
    const uint32_t* hp = h2 + (size_t)blk*(SEGLEN/2)*HDIM + j;
    float acc = 0.f;
    #pragma unroll 8
    for (int si2=0; si2<SEGLEN/2; ++si2){
        const uint32_t pk = hp[(size_t)si2*HDIM];
        const float hlo = __int_as_float(pk << 16);
        const float hhi = __int_as_float(pk & 0xffff0000u);
        acc = fmaf(wb[2*si2  ], hlo, acc);
        acc = fmaf(wb[2*si2+1], hhi, acc);
    }
    ctxp[(size_t)blk*HDIM + j] = acc;
}

// ---------------- K5: out[b] = (sum_seg ctxp) . out_W + out_b ----------------
__global__ __launch_bounds__(512) void k5_out(const float* __restrict__ ctxp, const float* __restrict__ out_W,
                                              const float* __restrict__ out_b, float* __restrict__ out)
{
    __shared__ float red[8];
    const int b = blockIdx.x, c = threadIdx.x;
    const int dir = c >> 8, j = c & (HDIM-1);
    float acc = 0.f;
    #pragma unroll
    for (int seg=0; seg<SEG; ++seg)
        acc += ctxp[((size_t)(b*2+dir)*SEG + seg)*HDIM + j];
    float p = acc * out_W[c];
    #pragma unroll
    for (int o=32;o;o>>=1) p += __shfl_xor(p,o,64);
    if ((c&63)==0) red[c>>6] = p;
    __syncthreads();
    if (c==0){
        float t = 0.f;
        #pragma unroll
        for (int r=0;r<8;++r) t += red[r];
        out[b] = t + out_b[0];
    }
}

extern "C" void kernel_launch(void* const* d_in, const int* in_sizes, int n_in,
                              void* d_out, int out_size, void* d_ws, size_t ws_size,
                              hipStream_t stream)
{
    const float* X     = (const float*)d_in[0];
    const float* emb   = (const float*)d_in[1];
    const float* num_W = (const float*)d_in[2];
    const float* num_b = (const float*)d_in[3];
    const float* Wf    = (const float*)d_in[4];
    const float* bf    = (const float*)d_in[5];
    const float* Wb    = (const float*)d_in[6];
    const float* bb    = (const float*)d_in[7];
    const float* Mu    = (const float*)d_in[8];
    const float* out_W = (const float*)d_in[9];
    const float* out_b = (const float*)d_in[10];
    float* out = (float*)d_out;

    float* ws = (float*)d_ws;
    size_t off = 0;
    float* swp   = ws + off; off += (size_t)BN*4*SN;           // 2 MB (4 partial rows per b)
    float* w     = ws + off; off += (size_t)BN*SN;             // 0.5 MB
    float* T     = ws + off; off += (size_t)2*VOCABN*TWOH;     // channel-paired, pre-scaled
    float* U     = ws + off; off += (size_t)2*8*TWOH;          // channel-paired, pre-scaled
    float* aArr  = ws + off; off += (size_t)BN*2*SEG*HDIM;     // 4 MB
    float* cArr  = ws + off; off += (size_t)BN*2*SEG*HDIM;     // 4 MB
    float* hstart= ws + off; off += (size_t)BN*2*SEG*HDIM;     // 4 MB
    float* ctxp  = ws + off; off += (size_t)BN*2*SEG*HDIM;     // 4 MB
    float* Xp    = ws + off; off += (size_t)BN*SN*8;           // 4 MB prepacked X
    uint32_t* h2 = (uint32_t*)(ws + off);
    off += (size_t)BN*2*SEG*(SEGLEN/2)*HDIM;                   // 128 MB packed bf16 h
    const bool useStore = ((size_t)off * sizeof(float)) <= ws_size;

    hipLaunchKernelGGL(k0_prep,     dim3(BN*SN/256),   dim3(256), 0, stream, X, Xp);
    hipLaunchKernelGGL(k1_tables,   dim3(2*VOCABN+2),  dim3(512), 0, stream,
                       emb, num_W, num_b, Wf, bf, Wb, bb, T, U);
    hipLaunchKernelGGL(k2_scan<0>,  dim3(BN*2*SEG),    dim3(128), 0, stream,
                       Xp, T, U, Mu, w, hstart, aArr, cArr, swp, ctxp, h2);
    hipLaunchKernelGGL(k_compose,   dim3(BN*2),        dim3(256), 0, stream,
                       aArr, cArr, hstart);
    if (useStore) {
        hipLaunchKernelGGL(k2_scan<1>, dim3(BN*2*SEG), dim3(128), 0, stream,
                           Xp, T, U, Mu, w, hstart, aArr, cArr, swp, ctxp, h2);
        hipLaunchKernelGGL(k3_softmax, dim3(BN),       dim3(256), 0, stream, swp, w);
        hipLaunchKernelGGL(k4_ctx,     dim3(BN*2*SEG), dim3(256), 0, stream, h2, w, ctxp);
    } else {
        hipLaunchKernelGGL(k2_scan<3>, dim3(BN*2*SEG), dim3(128), 0, stream,
                           Xp, T, U, Mu, w, hstart, aArr, cArr, swp, ctxp, h2);
        hipLaunchKernelGGL(k3_softmax, dim3(BN),       dim3(256), 0, stream, swp, w);
        hipLaunchKernelGGL(k2_scan<2>, dim3(BN*2*SEG), dim3(128), 0, stream,
                           Xp, T, U, Mu, w, hstart, aArr, cArr, swp, ctxp, h2);
    }
    hipLaunchKernelGGL(k5_out,      dim3(BN),          dim3(512), 0, stream,
                       ctxp, out_W, out_b, out);
}

// Round 16
// 147.633 us; speedup vs baseline: 1.4586x; 1.0245x over previous
//
#include <hip/hip_runtime.h>
#include <stdint.h>

#define VOCABN 64
#define EMBN   128
#define HDIM   256
#define NUMIN  7
#define BN     64
#define SN     2048
#define TWOH   512
#define SEG    32
#define SEGLEN 64

#define CZ 2.8853900818f   // 2*log2(e)
#define CF 1.4426950409f   // log2(e)

__device__ __forceinline__ float rcpf(float x){ return __builtin_amdgcn_rcpf(x); }

__device__ __forceinline__ float fast_exp2(float x){
#if __has_builtin(__builtin_amdgcn_exp2f)
    return __builtin_amdgcn_exp2f(x);
#else
    return exp2f(x);
#endif
}

// v_pk_fma_f32 with src0 broadcast from LO half (both result lanes use src0.lo)
__device__ __forceinline__ float2 pk_fma_blo(float2 a, float2 b, float2 c){
    float2 d;
    asm("v_pk_fma_f32 %0, %1, %2, %3 op_sel_hi:[0,1,1]" : "=v"(d) : "v"(a), "v"(b), "v"(c));
    return d;
}
// v_pk_fma_f32 with src0 broadcast from HI half
__device__ __forceinline__ float2 pk_fma_bhi(float2 a, float2 b, float2 c){
    float2 d;
    asm("v_pk_fma_f32 %0, %1, %2, %3 op_sel:[1,0,0] op_sel_hi:[1,1,1]" : "=v"(d) : "v"(a), "v"(b), "v"(c));
    return d;
}

// pack two f32 -> two bf16 (RNE) in one dword: lo16 = bf16(a), hi16 = bf16(b)
__device__ __forceinline__ uint32_t cvt_pk_bf16(float a, float b){
    uint32_t r;
    asm("v_cvt_pk_bf16_f32 %0, %1, %2" : "=v"(r) : "v"(a), "v"(b));
    return r;
}

// 64-lane sum via DPP; result valid in lane 63.
__device__ __forceinline__ float waveRedDpp(float x){
    x += __int_as_float(__builtin_amdgcn_update_dpp(0, __float_as_int(x), 0x111, 0xf, 0xf, false)); // row_shr:1
    x += __int_as_float(__builtin_amdgcn_update_dpp(0, __float_as_int(x), 0x112, 0xf, 0xf, false)); // row_shr:2
    x += __int_as_float(__builtin_amdgcn_update_dpp(0, __float_as_int(x), 0x114, 0xf, 0xf, false)); // row_shr:4
    x += __int_as_float(__builtin_amdgcn_update_dpp(0, __float_as_int(x), 0x118, 0xf, 0xf, false)); // row_shr:8
    x += __int_as_float(__builtin_amdgcn_update_dpp(0, __float_as_int(x), 0x142, 0xa, 0xf, false)); // row_bcast:15
    x += __int_as_float(__builtin_amdgcn_update_dpp(0, __float_as_int(x), 0x143, 0xc, 0xf, false)); // row_bcast:31
    return x;
}

// ---------------- K0: prepack X rows ----------------
// X'[row] = [n0 n1 n2 n3 | n4 n5 n6 evByteOffsetBits]
__global__ __launch_bounds__(256) void k0_prep(const float* __restrict__ X, float* __restrict__ Xp)
{
    const int r = blockIdx.x*256 + threadIdx.x;     // r < BN*SN
    const float4* src = (const float4*)(X + (size_t)r*8);
    const float4 a = src[0], b4 = src[1];
    float4* dst = (float4*)(Xp + (size_t)r*8);
    dst[0] = make_float4(a.y, a.z, a.w, b4.x);
    dst[1] = make_float4(b4.y, b4.z, b4.w, __int_as_float((int)a.x * (HDIM*8)));
}

// ---------------- K1: fold emb/bias/num path into CHANNEL-PAIRED, PRE-SCALED tables ----------------
// T'[(dir,v,j)] = float4(CZ*z_j, CF*f_j, CZ*z_{j+128}, CF*f_{j+128})  (j<128; row = 2048B)
// U'[(dir,i,j)] likewise.  (UNCHANGED from round 15)
__global__ __launch_bounds__(512) void k1_tables(
    const float* __restrict__ emb, const float* __restrict__ num_W, const float* __restrict__ num_b,
    const float* __restrict__ Wf, const float* __restrict__ bf,
    const float* __restrict__ Wb, const float* __restrict__ bb,
    float* __restrict__ T, float* __restrict__ U)
{
    const int blk = blockIdx.x;
    const int c = threadIdx.x;
    const int jj = c & (HDIM-1);        // channel 0..255
    const int g = c >> 8;               // 0 -> z gate, 1 -> f gate
    const int col = g*HDIM + jj;
    const float gs = g ? CF : CZ;
    const int comp = ((jj >> 7) << 1) + g;      // float4 component
    const int rowj = jj & 127;                  // float4 index within row
    if (blk < 2*VOCABN) {
        const int dir = blk & 1, v = blk >> 1;
        const float* W    = dir ? Wb : Wf;
        const float* bias = dir ? bb : bf;
        float acc = bias[col];
        const float* e = emb + (size_t)v*EMBN;
        #pragma unroll 8
        for (int k=0;k<EMBN;++k) acc = fmaf(e[k], W[(size_t)k*768 + col], acc);
        #pragma unroll
        for (int m=0;m<4;++m)    acc = fmaf(num_b[m], W[(size_t)(EMBN+m)*768 + col], acc);
        T[(((size_t)dir*VOCABN + v)*128 + rowj)*4 + comp] = acc * gs;
    } else {
        const int dir = blk - 2*VOCABN;
        const float* W = dir ? Wb : Wf;
        #pragma unroll
        for (int i=0;i<NUMIN;++i){
            float acc = 0.f;
            #pragma unroll
            for (int m=0;m<4;++m) acc = fmaf(num_W[i*4+m], W[(size_t)(EMBN+m)*768 + col], acc);
            U[(((size_t)dir*8 + i)*128 + rowj)*4 + comp] = acc * gs;
        }
    }
}

// ---------------- K2: segmented fo-pool scan, 4 channels/thread, 64-thread blocks ----------------
// Thread j owns channels j, j+64, j+128, j+192 via T-row dwordx4s at j*16 and j*16+1024.
// MODE 0: a=prod(f), c=scan from 0.  MODE 1: scan + scores + h2 store.
// MODE 2: ctx recompute fallback.    MODE 3: scores only (no-h2 fallback).
template<int MODE>
__global__ __launch_bounds__(64) void k2_scan(
    const float* __restrict__ Xp, const float* __restrict__ T, const float* __restrict__ U,
    const float* __restrict__ Mu, const float* __restrict__ w,
    const float* __restrict__ hstart,
    float* __restrict__ aArr, float* __restrict__ cArr,
    float* __restrict__ swp, float* __restrict__ ctxp, uint32_t* __restrict__ h2)
{
    const int bid = blockIdx.x;
    const int seg = bid & (SEG-1);
    const int dir = (bid >> 5) & 1;
    const int b   = bid >> 6;
    const int j   = threadIdx.x;            // 0..63
    const int blk = (b*2+dir)*SEG + seg;
    const size_t segIdx = (size_t)blk*HDIM + j;   // channels j, +64, +128, +192

    const char* Tb = (const char*)T + (size_t)dir*VOCABN*2048;  // row = 2048B
    const float4* Ud4 = (const float4*)U + (size_t)dir*8*128;
    // uA rows cover (ch j, ch j+128); uB rows cover (ch j+64, ch j+192)
    float2 uA0[NUMIN], uA1[NUMIN], uB0[NUMIN], uB1[NUMIN];
    #pragma unroll
    for (int i=0;i<NUMIN;++i){
        const float4 qa = Ud4[i*128 + j];
        const float4 qb = Ud4[i*128 + j + 64];
        uA0[i] = make_float2(qa.x, qa.y);  uA1[i] = make_float2(qa.z, qa.w);
        uB0[i] = make_float2(qb.x, qb.y);  uB1[i] = make_float2(qb.z, qb.w);
    }
    float muA0=0.f, muB0=0.f, muA1=0.f, muB1=0.f;
    if (MODE==1 || MODE==3){
        muA0 = Mu[dir*HDIM + j];       muB0 = Mu[dir*HDIM + j + 64];
        muA1 = Mu[dir*HDIM + j + 128]; muB1 = Mu[dir*HDIM + j + 192];
    }

    const int sBeg = seg*SEGLEN;
    const float* wb = w + (size_t)b*SN + sBeg;     // MODE2 fallback weights
    const int j16 = j*16;

    __shared__ float4 xlds[SEGLEN+4][2];   // [n0 n1 n2 n3][n4 n5 n6 evbits], +4 pad rows
    __shared__ int    evb[SEGLEN+4];       // T-row byte offsets (ev*2048)

    {   // staging: chunk c = (row, half); thread j stages chunks j, j+64; threads 0..7 pads
        auto stage = [&](int c){
            const int r = c >> 1, half = c & 1;
            const int rr = (r < SEGLEN) ? r : SEGLEN-1;
            const int spos = sBeg + rr;
            const int gp = b*SN + (dir ? (SN-1-spos) : spos);
            const float4 v4 = *(const float4*)(Xp + (size_t)gp*8 + half*4);
            xlds[r][half] = v4;
            if (half) evb[r] = __float_as_int(v4.w);
        };
        stage(j); stage(j + 64);
        if (j < 8) stage(128 + j);
    }
    __syncthreads();

    float hA0, hA1, hB0, hB1;
    if (MODE==0){ hA0=hA1=hB0=hB1=0.f; }
    else {
        hA0 = hstart[segIdx];       hB0 = hstart[segIdx + 64];
        hA1 = hstart[segIdx + 128]; hB1 = hstart[segIdx + 192];
    }
    float aA0=1.f, aA1=1.f, aB0=1.f, aB1=1.f;
    float cA0=0.f, cA1=0.f, cB0=0.f, cB1=0.f;
    float* swpp = swp + (size_t)(b*2 + dir)*SN + sBeg;
    uint32_t* h2p = h2 + (size_t)blk*SEGLEN*128 + j;

    // prologue: X ring depth 2, T ring depth 2 (two dwordx4 each), ev 1 ahead
    float4 xa0 = xlds[0][0], xb0 = xlds[0][1];
    float4 xa1 = xlds[1][0], xb1 = xlds[1][1];
    int e2 = evb[2];
    const char* tq0 = Tb + (uint32_t)evb[0];
    const char* tq1 = Tb + (uint32_t)evb[1];
    float4 tA0 = *(const float4*)(tq0 + j16), tB0 = *(const float4*)(tq0 + j16 + 1024);
    float4 tA1 = *(const float4*)(tq1 + j16), tB1 = *(const float4*)(tq1 + j16 + 1024);

    #pragma unroll 4
    for (int si=0; si<SEGLEN; ++si){
        // prefetch: T row si+2 (ev read 1 iter ago), X row si+2, ev row si+3
        const char* tq2 = Tb + (uint32_t)e2;
        const float4 tA2 = *(const float4*)(tq2 + j16);
        const float4 tB2 = *(const float4*)(tq2 + j16 + 1024);
        const float4 xan = xlds[si+2][0];
        const float4 xbn = xlds[si+2][1];
        const int en = evb[si+3];

        const float2 xp01 = make_float2(xa0.x, xa0.y);
        const float2 xp23 = make_float2(xa0.z, xa0.w);
        const float2 xp45 = make_float2(xb0.x, xb0.y);
        const float2 xp6e = make_float2(xb0.z, xb0.w);
        float2 zA0 = make_float2(tA0.x, tA0.y);
        float2 zA1 = make_float2(tA0.z, tA0.w);
        float2 zB0 = make_float2(tB0.x, tB0.y);
        float2 zB1 = make_float2(tB0.z, tB0.w);
        zA0 = pk_fma_blo(xp01, uA0[0], zA0); zA1 = pk_fma_blo(xp01, uA1[0], zA1);
        zB0 = pk_fma_blo(xp01, uB0[0], zB0); zB1 = pk_fma_blo(xp01, uB1[0], zB1);
        zA0 = pk_fma_bhi(xp01, uA0[1], zA0); zA1 = pk_fma_bhi(xp01, uA1[1], zA1);
        zB0 = pk_fma_bhi(xp01, uB0[1], zB0); zB1 = pk_fma_bhi(xp01, uB1[1], zB1);
        zA0 = pk_fma_blo(xp23, uA0[2], zA0); zA1 = pk_fma_blo(xp23, uA1[2], zA1);
        zB0 = pk_fma_blo(xp23, uB0[2], zB0); zB1 = pk_fma_blo(xp23, uB1[2], zB1);
        zA0 = pk_fma_bhi(xp23, uA0[3], zA0); zA1 = pk_fma_bhi(xp23, uA1[3], zA1);
        zB0 = pk_fma_bhi(xp23, uB0[3], zB0); zB1 = pk_fma_bhi(xp23, uB1[3], zB1);
        zA0 = pk_fma_blo(xp45, uA0[4], zA0); zA1 = pk_fma_blo(xp45, uA1[4], zA1);
        zB0 = pk_fma_blo(xp45, uB0[4], zB0); zB1 = pk_fma_blo(xp45, uB1[4], zB1);
        zA0 = pk_fma_bhi(xp45, uA0[5], zA0); zA1 = pk_fma_bhi(xp45, uA1[5], zA1);
        zB0 = pk_fma_bhi(xp45, uB0[5], zB0); zB1 = pk_fma_bhi(xp45, uB1[5], zB1);
        zA0 = pk_fma_blo(xp6e, uA0[6], zA0); zA1 = pk_fma_blo(xp6e, uA1[6], zA1);
        zB0 = pk_fma_blo(xp6e, uB0[6], zB0); zB1 = pk_fma_blo(xp6e, uB1[6], zB1);

        // gates, one reciprocal per channel (z pre-scaled by CZ/CF)
        {
            const float e2z = fast_exp2(zA0.x), ef = fast_exp2(zA0.y);
            const float a2 = 1.f + e2z, a1 = 1.f + ef;
            const float r_ = rcpf(a1 * a2);
            hA0 = fmaf(ef * hA0, a2, e2z - 1.f) * r_;
            if (MODE==0) aA0 *= ef * a2 * r_;
        }
        {
            const float e2z = fast_exp2(zA1.x), ef = fast_exp2(zA1.y);
            const float a2 = 1.f + e2z, a1 = 1.f + ef;
            const float r_ = rcpf(a1 * a2);
            hA1 = fmaf(ef * hA1, a2, e2z - 1.f) * r_;
            if (MODE==0) aA1 *= ef * a2 * r_;
        }
        {
            const float e2z = fast_exp2(zB0.x), ef = fast_exp2(zB0.y);
            const float a2 = 1.f + e2z, a1 = 1.f + ef;
            const float r_ = rcpf(a1 * a2);
            hB0 = fmaf(ef * hB0, a2, e2z - 1.f) * r_;
            if (MODE==0) aB0 *= ef * a2 * r_;
        }
        {
            const float e2z = fast_exp2(zB1.x), ef = fast_exp2(zB1.y);
            const float a2 = 1.f + e2z, a1 = 1.f + ef;
            const float r_ = rcpf(a1 * a2);
            hB1 = fmaf(ef * hB1, a2, e2z - 1.f) * r_;
            if (MODE==0) aB1 *= ef * a2 * r_;
        }

        if (MODE==1 || MODE==3){
            float pr = fmaf(hB1, muB1, fmaf(hA1, muA1, fmaf(hB0, muB0, hA0 * muA0)));
            pr = waveRedDpp(pr);
            if (j == 63) swpp[si] = pr;
            if (MODE==1){
                h2p[si*128]      = cvt_pk_bf16(hA0, hA1);   // slot j   = (ch j,    ch j+128)
                h2p[si*128 + 64] = cvt_pk_bf16(hB0, hB1);   // slot j+64= (ch j+64, ch j+192)
            }
        } else if (MODE==2){
            const float ws_ = wb[si];
            cA0 = fmaf(ws_, hA0, cA0); cA1 = fmaf(ws_, hA1, cA1);
            cB0 = fmaf(ws_, hB0, cB0); cB1 = fmaf(ws_, hB1, cB1);
        }
        // rotate rings
        xa0=xa1; xb0=xb1; xa1=xan; xb1=xbn;
        tA0=tA1; tB0=tB1; tA1=tA2; tB1=tB2; e2=en;
    }
    if (MODE==0){
        aArr[segIdx] = aA0;  aArr[segIdx+64] = aB0;  aArr[segIdx+128] = aA1;  aArr[segIdx+192] = aB1;
        cArr[segIdx] = hA0;  cArr[segIdx+64] = hB0;  cArr[segIdx+128] = hA1;  cArr[segIdx+192] = hB1;
    }
    if (MODE==2){
        ctxp[segIdx] = cA0;  ctxp[segIdx+64] = cB0;  ctxp[segIdx+128] = cA1;  ctxp[segIdx+192] = cB1;
    }
}

// ---------------- compose: hstart[seg] = h; h = a*h + c ----------------
__global__ __launch_bounds__(256) void k_compose(const float* __restrict__ aArr, const float* __restrict__ cArr,
                                                 float* __restrict__ hstart)
{
    const int bd = blockIdx.x;   // b*2 + dir
    const int j  = threadIdx.x;
    float h = 0.f;
    #pragma unroll
    for (int seg=0; seg<SEG; ++seg){
        const size_t idx = ((size_t)bd*SEG + seg)*HDIM + j;
        hstart[idx] = h;
        h = fmaf(aArr[idx], h, cArr[idx]);
    }
}

// ---------------- K3: softmax over S per batch (2 partial rows per b: dir 0/1) ----------------
__global__ __launch_bounds__(256) void k3_softmax(const float* __restrict__ swp, float* __restrict__ w)
{
    __shared__ float sc[SN];
    __shared__ float red[4];
    const int b = blockIdx.x, t = threadIdx.x;
    for (int s=t; s<SN; s+=256){
        float acc = 0.f;
        #pragma unroll
        for (int r=0;r<2;++r) acc += swp[((size_t)b*2 + r)*SN + s];
        sc[s] = acc;
    }
    __syncthreads();
    float m = -3.4e38f;
    for (int s=t; s<SN; s+=256) m = fmaxf(m, sc[s]);
    #pragma unroll
    for (int o=32;o;o>>=1) m = fmaxf(m, __shfl_xor(m,o,64));
    if ((t&63)==0) red[t>>6] = m;
    __syncthreads();
    m = fmaxf(fmaxf(red[0],red[1]), fmaxf(red[2],red[3]));
    float zs = 0.f;
    for (int s=t; s<SN; s+=256){
        float e = __expf(sc[s]-m);
        sc[s] = e;
        zs += e;
    }
    #pragma unroll
    for (int o=32;o;o>>=1) zs += __shfl_xor(zs,o,64);
    __syncthreads();
    if ((t&63)==0) red[t>>6] = zs;
    __syncthreads();
    zs = red[0]+red[1]+red[2]+red[3];
    float invz = rcpf(zs);
    for (int s=t; s<SN; s+=256) w[(size_t)b*SN + s] = sc[s]*invz;
}

// ---------------- K4: ctx from stored bf16 h (memory-bound replay) ----------------
// h2 layout: [blk][si][p in 0..128): dword = (bf16 ch p, bf16 ch p+128)
__global__ __launch_bounds__(128) void k4_ctx(const uint32_t* __restrict__ h2, const float* __restrict__ w,
                                              float* __restrict__ ctxp)
{
    const int bid = blockIdx.x;
    const int seg = bid & (SEG-1);
    const int dir = (bid >> 5) & 1;
    const int b   = bid >> 6;
    const int blk = (b*2+dir)*SEG + seg;
    const int p   = threadIdx.x;            // 0..127
    const float* wb = w + (size_t)b*SN + seg*SEGLEN;
    const uint32_t* hp = h2 + (size_t)blk*SEGLEN*128 + p;
    float acc0 = 0.f, acc1 = 0.f;
    #pragma unroll 8
    for (int si=0; si<SEGLEN; ++si){
        const uint32_t pk = hp[si*128];
        const float hv0 = __int_as_float(pk << 16);          // ch p
        const float hv1 = __int_as_float(pk & 0xffff0000u);  // ch p+128
        const float ws_ = wb[si];
        acc0 = fmaf(ws_, hv0, acc0);
        acc1 = fmaf(ws_, hv1, acc1);
    }
    ctxp[(size_t)blk*HDIM + p]       = acc0;
    ctxp[(size_t)blk*HDIM + p + 128] = acc1;
}

// ---------------- K5: out[b] = (sum_seg ctxp) . out_W + out_b ----------------
__global__ __launch_bounds__(512) void k5_out(const float* __restrict__ ctxp, const float* __restrict__ out_W,
                                              const float* __restrict__ out_b, float* __restrict__ out)
{
    __shared__ float red[8];
    const int b = blockIdx.x, c = threadIdx.x;
    const int dir = c >> 8, j = c & (HDIM-1);
    float acc = 0.f;
    #pragma unroll
    for (int seg=0; seg<SEG; ++seg)
        acc += ctxp[((size_t)(b*2+dir)*SEG + seg)*HDIM + j];
    float p = acc * out_W[c];
    #pragma unroll
    for (int o=32;o;o>>=1) p += __shfl_xor(p,o,64);
    if ((c&63)==0) red[c>>6] = p;
    __syncthreads();
    if (c==0){
        float t = 0.f;
        #pragma unroll
        for (int r=0;r<8;++r) t += red[r];
        out[b] = t + out_b[0];
    }
}

extern "C" void kernel_launch(void* const* d_in, const int* in_sizes, int n_in,
                              void* d_out, int out_size, void* d_ws, size_t ws_size,
                              hipStream_t stream)
{
    const float* X     = (const float*)d_in[0];
    const float* emb   = (const float*)d_in[1];
    const float* num_W = (const float*)d_in[2];
    const float* num_b = (const float*)d_in[3];
    const float* Wf    = (const float*)d_in[4];
    const float* bf    = (const float*)d_in[5];
    const float* Wb    = (const float*)d_in[6];
    const float* bb    = (const float*)d_in[7];
    const float* Mu    = (const float*)d_in[8];
    const float* out_W = (const float*)d_in[9];
    const float* out_b = (const float*)d_in[10];
    float* out = (float*)d_out;

    float* ws = (float*)d_ws;
    size_t off = 0;
    float* swp   = ws + off; off += (size_t)BN*2*SN;           // 1 MB (1 row per (b,dir))
    float* w     = ws + off; off += (size_t)BN*SN;             // 0.5 MB
    float* T     = ws + off; off += (size_t)2*VOCABN*TWOH;     // channel-paired, pre-scaled
    float* U     = ws + off; off += (size_t)2*8*TWOH;          // channel-paired, pre-scaled
    float* aArr  = ws + off; off += (size_t)BN*2*SEG*HDIM;     // 4 MB
    float* cArr  = ws + off; off += (size_t)BN*2*SEG*HDIM;     // 4 MB
    float* hstart= ws + off; off += (size_t)BN*2*SEG*HDIM;     // 4 MB
    float* ctxp  = ws + off; off += (size_t)BN*2*SEG*HDIM;     // 4 MB
    float* Xp    = ws + off; off += (size_t)BN*SN*8;           // 4 MB prepacked X
    uint32_t* h2 = (uint32_t*)(ws + off);
    off += (size_t)BN*2*SEG*SEGLEN*128;                        // 134 MB packed bf16 h
    const bool useStore = ((size_t)off * sizeof(float)) <= ws_size;

    hipLaunchKernelGGL(k0_prep,     dim3(BN*SN/256),   dim3(256), 0, stream, X, Xp);
    hipLaunchKernelGGL(k1_tables,   dim3(2*VOCABN+2),  dim3(512), 0, stream,
                       emb, num_W, num_b, Wf, bf, Wb, bb, T, U);
    hipLaunchKernelGGL(k2_scan<0>,  dim3(BN*2*SEG),    dim3(64), 0, stream,
                       Xp, T, U, Mu, w, hstart, aArr, cArr, swp, ctxp, h2);
    hipLaunchKernelGGL(k_compose,   dim3(BN*2),        dim3(256), 0, stream,
                       aArr, cArr, hstart);
    if (useStore) {
        hipLaunchKernelGGL(k2_scan<1>, dim3(BN*2*SEG), dim3(64), 0, stream,
                           Xp, T, U, Mu, w, hstart, aArr, cArr, swp, ctxp, h2);
        hipLaunchKernelGGL(k3_softmax, dim3(BN),       dim3(256), 0, stream, swp, w);
        hipLaunchKernelGGL(k4_ctx,     dim3(BN*2*SEG), dim3(128), 0, stream, h2, w, ctxp);
    } else {
        hipLaunchKernelGGL(k2_scan<3>, dim3(BN*2*SEG), dim3(64), 0, stream,
                           Xp, T, U, Mu, w, hstart, aArr, cArr, swp, ctxp, h2);
        hipLaunchKernelGGL(k3_softmax, dim3(BN),       dim3(256), 0, stream, swp, w);
        hipLaunchKernelGGL(k2_scan<2>, dim3(BN*2*SEG), dim3(64), 0, stream,
                           Xp, T, U, Mu, w, hstart, aArr, cArr, swp, ctxp, h2);
    }
    hipLaunchKernelGGL(k5_out,      dim3(BN),          dim3(512), 0, stream,
                       ctxp, out_W, out_b, out);
}